// Round 8
// baseline (730.395 us; speedup 1.0000x reference)
//
#include <hip/hip_runtime.h>
#include <hip/hip_bf16.h>
#include <math.h>

typedef unsigned short u16;
typedef short s16x8 __attribute__((ext_vector_type(8)));
typedef float f32x4v __attribute__((ext_vector_type(4)));
typedef int i32x4 __attribute__((ext_vector_type(4)));
typedef unsigned short u16x4 __attribute__((ext_vector_type(4)));

#define EDIM 300
#define EPAD 320
#define VOCAB 50000

// ---- fixed workspace layout (bytes) ----
static constexpr size_t SZ_WIH  = (size_t)2 * 1024 * EPAD * 2;   // bf16 [2][1024 pack][320]
static constexpr size_t SZ_WPK  = (size_t)2 * 1024 * 256;        // i8 packed Whh frags
static constexpr size_t SZ_SW   = (size_t)2 * 1024 * 4;          // f32 per-row scale (pack order)
static constexpr size_t SZ_BIAS = (size_t)2 * 1024 * 4;          // f32 (pack order)
static constexpr size_t SZ_HSV  = (size_t)2 * 256 * 256;         // i8 h chunk-boundary save
static constexpr size_t SZ_CST  = (size_t)2 * 256 * 256 * 4;     // f32 c-state
static constexpr size_t SZ_VAC  = (size_t)2 * 256 * 256 * 4;     // f32 vacc-state
static constexpr size_t SZ_VOUT = (size_t)2 * 128 * 512 * 4;     // f32 [2][128][512]
static constexpr size_t SZ_EMB  = (size_t)VOCAB * EPAD * 2;      // bf16 emb table padded (32 MB)
static constexpr size_t FIXED_B = SZ_WIH + SZ_WPK + SZ_SW + SZ_BIAS + SZ_HSV + SZ_CST + SZ_VAC + SZ_VOUT + SZ_EMB;
static constexpr size_t PER_T   = (size_t)512 * 1024 * 2;        // ginc per step (1 MB)

// pack permutation: pack p = w*128 + q*16 + ul  (w=wave 0..7, q=uh*4+gate, ul 0..15)
//   -> logical Whh/Wih row jlog = gate*256 + w*32 + uh*16 + ul
// sigma (ginc column) s = w*128 + uh*64 + ul*4 + gate  (gates contiguous per cell)

__device__ __forceinline__ float bf2f(u16 u) {
  union { float f; unsigned int i; } v; v.i = ((unsigned int)u) << 16; return v.f;
}
__device__ __forceinline__ u16 f2bf(float f) {
  union { float f; unsigned int i; } v; v.f = f;
  unsigned int r = v.i + 0x7fffu + ((v.i >> 16) & 1u);   // RNE (finite inputs)
  return (u16)(r >> 16);
}
__device__ __forceinline__ void gload_lds16(const void* g, void* l) {
  __builtin_amdgcn_global_load_lds((const __attribute__((address_space(1))) void*)g,
                                   (__attribute__((address_space(3))) void*)l, 16, 0, 0);
}
// order LDS ops across waves WITHOUT draining vmcnt
__device__ __forceinline__ void lds_barrier() {
  asm volatile("s_waitcnt lgkmcnt(0)" ::: "memory");
  __builtin_amdgcn_s_barrier();
}

// ---------------- prep: Wih->bf16 padded (pack-row order), bias sum (pack order) ----------------
__global__ void prep_kernel(const float* wih_f, const float* bih_f, const float* bhh_f,
                            const float* wih_b, const float* bih_b, const float* bhh_b,
                            u16* wih_bf, float* bias)
{
  int tid = blockIdx.x * blockDim.x + threadIdx.x;
  if (tid < 2 * 1024 * EPAD) {
    int d = tid / (1024 * EPAD); int rr = tid % (1024 * EPAD);
    int p = rr / EPAD; int k = rr % EPAD;
    int w = p >> 7, q = (p >> 4) & 7, ul = p & 15;
    int jlog = (q & 3) * 256 + w * 32 + (q >> 2) * 16 + ul;
    const float* wsrc = d ? wih_b : wih_f;
    wih_bf[tid] = (k < EDIM) ? f2bf(wsrc[(size_t)jlog * EDIM + k]) : (u16)0;
  }
  int t2 = tid - 2 * 1024 * EPAD;
  if (t2 >= 0 && t2 < 2 * 1024) {
    int d = t2 >> 10; int p = t2 & 1023;
    int w = p >> 7, q = (p >> 4) & 7, ul = p & 15;
    int jlog = (q & 3) * 256 + w * 32 + (q >> 2) * 16 + ul;
    bias[t2] = d ? (bih_b[jlog] + bhh_b[jlog]) : (bih_f[jlog] + bhh_f[jlog]);
  }
}

// ---------------- emb -> bf16, K padded 300->320 (one-time) ----------------
__global__ void embconv_kernel(const float* emb, u16* embbf)
{
  int r = blockIdx.x;
  int k = threadIdx.x;     // 320
  embbf[(size_t)r * EPAD + k] = (k < EDIM) ? f2bf(emb[(size_t)r * EDIM + k]) : (u16)0;
}

// ---------------- Whh -> i8 quant + MFMA-fragment pack (8-wave pack order) ----------------
__global__ void whhq_kernel(const float* whh_f, const float* whh_b, char* wpk, float* sw)
{
  int jp = blockIdx.x;             // 0..2047 = d*1024 + pack p
  int t = threadIdx.x;             // 64
  int d = jp >> 10, p = jp & 1023;
  int w = p >> 7, q = (p >> 4) & 7, ul = p & 15;
  int jlog = (q & 3) * 256 + w * 32 + (q >> 2) * 16 + ul;
  const float* src = (d ? whh_b : whh_f) + (size_t)jlog * 256;
  float v[4]; float m = 0.f;
  #pragma unroll
  for (int kk = 0; kk < 4; ++kk) { v[kk] = src[t * 4 + kk]; m = fmaxf(m, fabsf(v[kk])); }
  #pragma unroll
  for (int off = 32; off > 0; off >>= 1) m = fmaxf(m, __shfl_xor(m, off));
  float sunit = m / 127.f;
  if (sunit < 1e-30f) sunit = 1e-30f;
  unsigned int pk = 0;
  #pragma unroll
  for (int kk = 0; kk < 4; ++kk) {
    int qv = (int)rintf(v[kk] / sunit);
    qv = qv > 127 ? 127 : (qv < -127 ? -127 : qv);
    pk |= ((unsigned int)(qv & 255)) << (8 * kk);
  }
  // frag entry (d,w,q,kc,lane=kg*16+ul): bytes = Wq[jlog][kc*64+kg*16 .. +16)
  size_t base = ((((size_t)(d * 8 + w) * 8 + q) * 4 + (t >> 4)) * 64
                 + (((t >> 2) & 3) * 16 + ul)) * 16 + (t & 3) * 4;
  *(unsigned int*)&wpk[base] = pk;
  if (t == 0) sw[jp] = sunit / 127.f;
}

// ---------------- fused gather + input projection GEMM for one chunk ----------------
// M-row m = (d*T + tl)*256 + R; B rows = pack order; epilogue stores sigma-permuted cols.
__global__ void __launch_bounds__(256, 2)
gemm_chunk_kernel(const int* __restrict__ x1, const int* __restrict__ x2,
                  const u16* __restrict__ embbf, const u16* __restrict__ wih_bf,
                  const float* __restrict__ bias, u16* __restrict__ ginc,
                  int t0, int T, int logT)
{
  __shared__ __align__(16) u16 smem[16384];     // As[8192] | Bs[8192]; epilogue: C[128][128]
  u16* As = smem;
  u16* Bs = smem + 8192;

  int m0 = blockIdx.x * 128;
  int d  = m0 >> (8 + logT);
  int tl = (m0 >> 8) & (T - 1);
  int R0 = m0 & 255;                 // 0 or 128
  int n0 = blockIdx.y * 128;         // = wave-slice w*128 of pack space
  int lane = threadIdx.x & 63;
  int w = threadIdx.x >> 6;
  int wm = w >> 1, wn = w & 1;

  const int* x = (R0 >> 7) ? x2 : x1;
  int t = t0 + tl;
  int tpos = d ? (255 - t) : t;

  int ar  = lane >> 3;
  int acb = (lane & 7) * 16;
  int sw  = ar << 4;

  int toks[4];
  #pragma unroll
  for (int i = 0; i < 4; ++i) {
    int lrow = (i * 4 + w) * 8 + ar;
    toks[i] = x[((R0 + lrow) & 127) * 256 + tpos];
  }

  f32x4v acc[4][4] = {};
  const char* Bbase = (const char*)(wih_bf + (size_t)d * 1024 * EPAD);
  const char* Ebase = (const char*)embbf;

  for (int kt = 0; kt < 5; ++kt) {
    int k0b = kt * 128;
    #pragma unroll
    for (int i = 0; i < 4; ++i) {
      int lrow = (i * 4 + w) * 8 + ar;
      gload_lds16(Ebase + (size_t)toks[i] * 640 + k0b + (acb ^ sw),
                  (char*)As + (i * 4 + w) * 1024);
      gload_lds16(Bbase + (size_t)(n0 + lrow) * 640 + k0b + (acb ^ sw),
                  (char*)Bs + (i * 4 + w) * 1024);
    }
    __syncthreads();
    #pragma unroll
    for (int kc = 0; kc < 2; ++kc) {
      s16x8 a[4], b[4];
      int cb = kc * 64 + (lane >> 4) * 16;
      #pragma unroll
      for (int mf = 0; mf < 4; ++mf) {
        int rr = wm * 64 + mf * 16 + (lane & 15);
        a[mf] = *(const s16x8*)((const char*)As + rr * 128 + (cb ^ ((rr & 7) << 4)));
      }
      #pragma unroll
      for (int nf = 0; nf < 4; ++nf) {
        int rr = wn * 64 + nf * 16 + (lane & 15);
        b[nf] = *(const s16x8*)((const char*)Bs + rr * 128 + (cb ^ ((rr & 7) << 4)));
      }
      #pragma unroll
      for (int mf = 0; mf < 4; ++mf)
        #pragma unroll
        for (int nf = 0; nf < 4; ++nf)
          acc[mf][nf] = __builtin_amdgcn_mfma_f32_16x16x32_bf16(a[mf], b[nf], acc[mf][nf], 0, 0, 0);
    }
    __syncthreads();
  }

  float bv[4];
  #pragma unroll
  for (int nf = 0; nf < 4; ++nf)
    bv[nf] = bias[d * 1024 + n0 + wn * 64 + nf * 16 + (lane & 15)];

  // stage C (bf16, pack cols) into LDS
  #pragma unroll
  for (int mf = 0; mf < 4; ++mf)
    #pragma unroll
    for (int nf = 0; nf < 4; ++nf) {
      int col = wn * 64 + nf * 16 + (lane & 15);
      #pragma unroll
      for (int i = 0; i < 4; ++i) {
        int row = wm * 64 + mf * 16 + (lane >> 4) * 4 + i;
        smem[row * 128 + col] = f2bf(acc[mf][nf][i] + bv[nf]);
      }
    }
  __syncthreads();
  // store with sigma col permutation: s = uh*64 + ul*4 + gate  <-  pack cl = (uh*4+gate)*16 + ul
  {
    size_t rowbase = ((size_t)(d * T + tl) * 256 + R0);
    int tid = threadIdx.x;
    #pragma unroll
    for (int it = 0; it < 8; ++it) {
      int chunk = it * 256 + tid;      // 2048 chunks of 8 u16
      int row = chunk >> 4;
      int s0 = (chunk & 15) * 8;
      s16x8 v;
      #pragma unroll
      for (int jj = 0; jj < 8; ++jj) {
        int s = s0 + jj;
        int gate = s & 3, ul = (s >> 2) & 15, uh = s >> 6;
        v[jj] = (short)smem[row * 128 + (uh * 4 + gate) * 16 + ul];
      }
      *(s16x8*)(ginc + (rowbase + row) * 1024 + n0 + s0) = v;
    }
  }
}

// ---------------- recurrent bi-LSTM: 512 blocks = 2 dir x 256 single-row streams ----------------
// 2 blocks/CU co-resident -> block A's gate phase overlaps block B's MFMA phase.
// 8 waves; wave w owns u in [w*32,(w+1)*32) x 4 gates (in-register gate math).
// ONE lgkm-only barrier per step; h double-buffered in LDS (256 B each).
__global__ void __launch_bounds__(512)
lstm_chunk_kernel(const u16* __restrict__ ginc, const i32x4* __restrict__ wpk,
                  const float* __restrict__ sw, char* hsave,
                  float* cstate, float* vaccst, float* vout,
                  const int* len1, const int* len2, int t0, int T)
{
  __shared__ __align__(16) char h_lds[2][288];      // [parity][256 k + pad]

  const int bid = blockIdx.x;
  const int d = bid >> 8, R = bid & 255;
  const int tid = threadIdx.x;
  const int lane = tid & 63, w = tid >> 6;          // 8 waves
  const int cl = lane & 15;

  // Whh i8 fragments -> registers; per-column scales (pack order)
  i32x4 bfr[8][4];
  #pragma unroll
  for (int q = 0; q < 8; ++q)
    #pragma unroll
    for (int kc = 0; kc < 4; ++kc)
      bfr[q][kc] = wpk[(((size_t)(d * 8 + w) * 8 + q) * 4 + kc) * 64 + lane];
  float swl[8];
  #pragma unroll
  for (int q = 0; q < 8; ++q)
    swl[q] = sw[d * 1024 + w * 128 + q * 16 + cl];

  if (tid < 256)
    h_lds[0][tid] = (t0 > 0) ? hsave[((size_t)d * 256 + R) * 256 + tid] : (char)0;

  int lm = ((R >> 7) ? len2 : len1)[R & 127] - 1;

  const bool gl = (lane < 16);
  float c[2] = {0.f, 0.f}, va[2] = {0.f, 0.f};
  if (t0 > 0 && gl) {
    #pragma unroll
    for (int uh = 0; uh < 2; ++uh) {
      size_t sidx = ((size_t)d * 256 + R) * 256 + (w * 32 + uh * 16 + cl);
      c[uh] = cstate[sidx];
      va[uh] = vaccst[sidx];
    }
  }

  const size_t GSTEP = (size_t)256 * 1024;
  const u16* gbase = ginc + ((size_t)d * T * 256 + R) * 1024;
  u16x4 gv[2];
  if (gl) {
    #pragma unroll
    for (int uh = 0; uh < 2; ++uh)
      gv[uh] = *(const u16x4*)(gbase + w * 128 + uh * 64 + cl * 4);
  }
  __syncthreads();

  const bool final_chunk = (t0 + T == 256);
  int par = 0;

  for (int tl = 0; tl < T; ++tl) {
    // prefetch next step's gates (stays in flight across the barrier)
    const u16* gnb = gbase + GSTEP * (size_t)((tl + 1 < T) ? tl + 1 : tl);
    u16x4 gvn[2];
    if (gl) {
      #pragma unroll
      for (int uh = 0; uh < 2; ++uh)
        gvn[uh] = *(const u16x4*)(gnb + w * 128 + uh * 64 + cl * 4);
    }

    // A-frags (row 0 real; rows 1-15 zero)
    i32x4 a[4] = {{0,0,0,0},{0,0,0,0},{0,0,0,0},{0,0,0,0}};
    if (cl == 0) {
      #pragma unroll
      for (int kc = 0; kc < 4; ++kc)
        a[kc] = *(const i32x4*)&h_lds[par][kc * 64 + (lane >> 4) * 16];
    }
    i32x4 acc[8];
    #pragma unroll
    for (int q = 0; q < 8; ++q) {
      i32x4 z = {0, 0, 0, 0};
      #pragma unroll
      for (int kc = 0; kc < 4; ++kc)
        z = __builtin_amdgcn_mfma_i32_16x16x64_i8(a[kc], bfr[q][kc], z, 0, 0, 0);
      acc[q] = z;
    }

    // in-register gate math on lanes 0..15 (cells: 2 uh per lane)
    if (gl) {
      int tmap = d ? (255 - (t0 + tl)) : (t0 + tl);
      #pragma unroll
      for (int uh = 0; uh < 2; ++uh) {
        float s0 = (float)acc[uh * 4 + 0][0] * swl[uh * 4 + 0] + bf2f(gv[uh][0]);
        float s1 = (float)acc[uh * 4 + 1][0] * swl[uh * 4 + 1] + bf2f(gv[uh][1]);
        float s2 = (float)acc[uh * 4 + 2][0] * swl[uh * 4 + 2] + bf2f(gv[uh][2]);
        float s3 = (float)acc[uh * 4 + 3][0] * swl[uh * 4 + 3] + bf2f(gv[uh][3]);
        float I = __builtin_amdgcn_rcpf(1.f + __expf(-s0));
        float F = __builtin_amdgcn_rcpf(1.f + __expf(-s1));
        float G = 1.f - 2.f * __builtin_amdgcn_rcpf(__expf(2.f * s2) + 1.f);
        float O = __builtin_amdgcn_rcpf(1.f + __expf(-s3));
        float cn = F * c[uh] + I * G;
        c[uh] = cn;
        float hn = O * (1.f - 2.f * __builtin_amdgcn_rcpf(__expf(2.f * cn) + 1.f));
        if (tmap < lm) va[uh] += hn;
        h_lds[par ^ 1][w * 32 + uh * 16 + cl] = (char)(int)rintf(hn * 127.f);
      }
    }
    lds_barrier();
    #pragma unroll
    for (int uh = 0; uh < 2; ++uh) gv[uh] = gvn[uh];
    par ^= 1;
  }

  if (gl) {
    #pragma unroll
    for (int uh = 0; uh < 2; ++uh) {
      int u = w * 32 + uh * 16 + cl;
      size_t sidx = ((size_t)d * 256 + R) * 256 + u;
      cstate[sidx] = c[uh];
      vaccst[sidx] = va[uh];
      if (final_chunk)
        vout[((size_t)(R >> 7) * 128 + (R & 127)) * 512 + d * 256 + u] = va[uh] / (float)lm;
    }
  }
  if (!final_chunk && tid < 256)
    hsave[((size_t)d * 256 + R) * 256 + tid] = h_lds[par][tid];
}

// ---------------- MLP head ----------------
__global__ void mlp_kernel(const float* v, const float* W1, const float* b1,
                           const float* W2, const float* b2, const float* Wo, const float* bo,
                           float* out)
{
  __shared__ float vec[512];
  __shared__ float a1[512];
  __shared__ float red[4];
  int b = blockIdx.x;
  int tid = threadIdx.x;   // 256
  for (int i = tid; i < 512; i += 256)
    vec[i] = fabsf(v[(size_t)b * 512 + i] - v[(size_t)(128 + b) * 512 + i]);
  __syncthreads();
  for (int j = tid; j < 512; j += 256) {
    float s = b1[j];
    const float* wr = W1 + (size_t)j * 512;
    for (int k = 0; k < 512; ++k) s += vec[k] * wr[k];
    a1[j] = fmaxf(s, 0.f);
  }
  __syncthreads();
  float s = b2[tid];
  {
    const float* wr = W2 + (size_t)tid * 512;
    for (int k = 0; k < 512; ++k) s += a1[k] * wr[k];
  }
  float p = fmaxf(s, 0.f) * Wo[tid];
  for (int off = 32; off > 0; off >>= 1) p += __shfl_down(p, off);
  if ((tid & 63) == 0) red[tid >> 6] = p;
  __syncthreads();
  if (tid == 0) {
    float logit = red[0] + red[1] + red[2] + red[3] + bo[0];
    out[b] = logit;
    out[128 + b] = 1.f / (1.f + __expf(-logit));
  }
}

extern "C" void kernel_launch(void* const* d_in, const int* in_sizes, int n_in,
                              void* d_out, int out_size, void* d_ws, size_t ws_size,
                              hipStream_t stream)
{
  const int*   x1    = (const int*)d_in[0];
  const int*   x2    = (const int*)d_in[1];
  const int*   len1  = (const int*)d_in[2];
  const int*   len2  = (const int*)d_in[3];
  const float* emb   = (const float*)d_in[4];
  const float* wih_f = (const float*)d_in[5];
  const float* whh_f = (const float*)d_in[6];
  const float* bih_f = (const float*)d_in[7];
  const float* bhh_f = (const float*)d_in[8];
  const float* wih_b = (const float*)d_in[9];
  const float* whh_b = (const float*)d_in[10];
  const float* bih_b = (const float*)d_in[11];
  const float* bhh_b = (const float*)d_in[12];
  const float* W1    = (const float*)d_in[13];
  const float* b1    = (const float*)d_in[14];
  const float* W2    = (const float*)d_in[15];
  const float* b2    = (const float*)d_in[16];
  const float* Wo    = (const float*)d_in[17];
  const float* bo    = (const float*)d_in[18];

  char* p = (char*)d_ws;
  u16*   wih_bf = (u16*)p;          p += SZ_WIH;
  char*  wpk    = (char*)p;         p += SZ_WPK;
  float* swp    = (float*)p;        p += SZ_SW;
  float* bias   = (float*)p;        p += SZ_BIAS;
  char*  hsave  = (char*)p;         p += SZ_HSV;
  float* cst    = (float*)p;        p += SZ_CST;
  float* vac    = (float*)p;        p += SZ_VAC;
  float* vout   = (float*)p;        p += SZ_VOUT;
  u16*   embbf  = (u16*)p;          p += SZ_EMB;

  int T = 256;
  while (T > 1 && FIXED_B + (size_t)T * PER_T > ws_size) T >>= 1;
  int logT = __builtin_ctz((unsigned)T);
  u16* ginc = (u16*)p;              // [(d*T+tl)*256 + R][1024 sigma-cols] u16

  {
    int total = 2 * 1024 * EPAD + 2 * 1024;
    prep_kernel<<<(total + 255) / 256, 256, 0, stream>>>(
        wih_f, bih_f, bhh_f, wih_b, bih_b, bhh_b, wih_bf, bias);
  }
  whhq_kernel<<<2048, 64, 0, stream>>>(whh_f, whh_b, wpk, swp);
  embconv_kernel<<<VOCAB, EPAD, 0, stream>>>(emb, embbf);

  int nch = 256 / T;
  for (int ch = 0; ch < nch; ++ch) {
    int tt0 = ch * T;
    gemm_chunk_kernel<<<dim3(4 * T, 8), 256, 0, stream>>>(x1, x2, embbf, wih_bf, bias,
                                                          ginc, tt0, T, logT);
    lstm_chunk_kernel<<<512, 512, 0, stream>>>(ginc, (const i32x4*)wpk, swp, hsave,
                                               cst, vac, vout, len1, len2, tt0, T);
  }

  mlp_kernel<<<128, 256, 0, stream>>>(vout, W1, b1, W2, b2, Wo, bo, (float*)d_out);
}

// Round 9
// 717.837 us; speedup vs baseline: 1.0175x; 1.0175x over previous
//
#include <hip/hip_runtime.h>
#include <hip/hip_bf16.h>
#include <math.h>

typedef unsigned short u16;
typedef unsigned int u32;
typedef short s16x8 __attribute__((ext_vector_type(8)));
typedef float f32x4v __attribute__((ext_vector_type(4)));
typedef int i32x4 __attribute__((ext_vector_type(4)));
typedef unsigned short u16x4 __attribute__((ext_vector_type(4)));

#define EDIM 300
#define EPAD 320
#define VOCAB 50000

// ---- fixed workspace layout (bytes) ----
static constexpr size_t SZ_WIH  = (size_t)2 * 1024 * EPAD * 2;   // bf16 [2][1024 pack][320]
static constexpr size_t SZ_WPK  = (size_t)2 * 1024 * 256;        // i8 packed Whh A-frags
static constexpr size_t SZ_SW   = (size_t)2 * 256 * 4;           // f32 per-u scale
static constexpr size_t SZ_BIAS = (size_t)2 * 1024 * 4;          // f32 (pack order)
static constexpr size_t SZ_HSV  = (size_t)32 * 4096;             // swizzled h LDS dumps (128 KB)
static constexpr size_t SZ_CST  = (size_t)2 * 256 * 256 * 4;     // f32 c-state
static constexpr size_t SZ_VAC  = (size_t)2 * 256 * 256 * 4;     // f32 vacc-state
static constexpr size_t SZ_VOUT = (size_t)2 * 128 * 512 * 4;     // f32 [2][128][512]
static constexpr size_t SZ_EMB  = (size_t)VOCAB * EPAD * 2;      // bf16 emb table padded (32 MB)
static constexpr size_t FIXED_B = SZ_WIH + SZ_WPK + SZ_SW + SZ_BIAS + SZ_HSV + SZ_CST + SZ_VAC + SZ_VOUT + SZ_EMB;
static constexpr size_t PER_T   = (size_t)512 * 1024 * 2;        // ginc per step (1 MB)

// pack permutation: pack row p = m*16 + uloc*4 + gate  (m = u>>2 in [0,64), uloc = u&3)
//   -> logical row jlog = gate*256 + u,  u = (p>>4)*4 + ((p>>2)&3), gate = p&3
// ginc layout per (d,tl) slab (262144 u16): [u 256][R 256][gate 4]

__device__ __forceinline__ float bf2f(u16 u) {
  union { float f; unsigned int i; } v; v.i = ((unsigned int)u) << 16; return v.f;
}
__device__ __forceinline__ u16 f2bf(float f) {
  union { float f; unsigned int i; } v; v.f = f;
  unsigned int r = v.i + 0x7fffu + ((v.i >> 16) & 1u);   // RNE (finite inputs)
  return (u16)(r >> 16);
}
__device__ __forceinline__ void gload_lds16(const void* g, void* l) {
  __builtin_amdgcn_global_load_lds((const __attribute__((address_space(1))) void*)g,
                                   (__attribute__((address_space(3))) void*)l, 16, 0, 0);
}
// order LDS ops across waves WITHOUT draining vmcnt
__device__ __forceinline__ void lds_barrier() {
  asm volatile("s_waitcnt lgkmcnt(0)" ::: "memory");
  __builtin_amdgcn_s_barrier();
}

// ---------------- prep: Wih->bf16 padded (pack-row order), bias sum (pack order) ----------------
__global__ void prep_kernel(const float* wih_f, const float* bih_f, const float* bhh_f,
                            const float* wih_b, const float* bih_b, const float* bhh_b,
                            u16* wih_bf, float* bias)
{
  int tid = blockIdx.x * blockDim.x + threadIdx.x;
  if (tid < 2 * 1024 * EPAD) {
    int d = tid / (1024 * EPAD); int rr = tid % (1024 * EPAD);
    int p = rr / EPAD; int k = rr % EPAD;
    int jlog = (p & 3) * 256 + (p >> 4) * 4 + ((p >> 2) & 3);
    const float* wsrc = d ? wih_b : wih_f;
    wih_bf[tid] = (k < EDIM) ? f2bf(wsrc[(size_t)jlog * EDIM + k]) : (u16)0;
  }
  int t2 = tid - 2 * 1024 * EPAD;
  if (t2 >= 0 && t2 < 2 * 1024) {
    int d = t2 >> 10; int p = t2 & 1023;
    int jlog = (p & 3) * 256 + (p >> 4) * 4 + ((p >> 2) & 3);
    bias[t2] = d ? (bih_b[jlog] + bhh_b[jlog]) : (bih_f[jlog] + bhh_f[jlog]);
  }
}

// ---------------- emb -> bf16, K padded 300->320 (one-time) ----------------
__global__ void embconv_kernel(const float* emb, u16* embbf)
{
  int r = blockIdx.x;
  int k = threadIdx.x;     // 320
  embbf[(size_t)r * EPAD + k] = (k < EDIM) ? f2bf(emb[(size_t)r * EDIM + k]) : (u16)0;
}

// ---------------- Whh -> i8 quant (per-u shared scale) + A-frag pack ----------------
// A-frag entry (d, m, kc): 64 lanes x 16B; lane = kg*16 + (uloc*4+gate), bytes = k in [kc*64+kg*16, +16)
__global__ void whhq_kernel(const float* whh_f, const float* whh_b, char* wpk, float* swu)
{
  int blk = blockIdx.x;            // 512 = d*256 + u
  int t = threadIdx.x;             // 64
  int d = blk >> 8, u = blk & 255;
  const float* W = d ? whh_b : whh_f;
  float v[4][4]; float m = 0.f;
  #pragma unroll
  for (int g = 0; g < 4; ++g) {
    const float* row = W + (size_t)(g * 256 + u) * 256 + t * 4;
    #pragma unroll
    for (int kk = 0; kk < 4; ++kk) { v[g][kk] = row[kk]; m = fmaxf(m, fabsf(v[g][kk])); }
  }
  #pragma unroll
  for (int off = 32; off > 0; off >>= 1) m = fmaxf(m, __shfl_xor(m, off));
  float sunit = fmaxf(m / 127.f, 1e-30f);
  int mm = u >> 2, uloc = u & 3;
  int k0 = t * 4;
  #pragma unroll
  for (int g = 0; g < 4; ++g) {
    unsigned pk = 0;
    #pragma unroll
    for (int kk = 0; kk < 4; ++kk) {
      int q = (int)rintf(v[g][kk] / sunit);
      q = q > 127 ? 127 : (q < -127 ? -127 : q);
      pk |= ((unsigned)(q & 255)) << (8 * kk);
    }
    int lanei = ((k0 >> 4) & 3) * 16 + uloc * 4 + g;
    size_t base = (((size_t)(d * 64 + mm) * 4 + (k0 >> 6)) * 64 + lanei) * 16 + (k0 & 15);
    *(unsigned*)&wpk[base] = pk;
  }
  if (t == 0) swu[blk] = sunit / 127.f;
}

// ---------------- fused gather + input projection GEMM for one chunk ----------------
__global__ void __launch_bounds__(256, 2)
gemm_chunk_kernel(const int* __restrict__ x1, const int* __restrict__ x2,
                  const u16* __restrict__ embbf, const u16* __restrict__ wih_bf,
                  const float* __restrict__ bias, u16* __restrict__ ginc,
                  int t0, int T, int logT)
{
  __shared__ __align__(16) u16 smem[16384];     // As[8192] | Bs[8192]; epilogue: C[128][128]
  u16* As = smem;
  u16* Bs = smem + 8192;

  int m0 = blockIdx.x * 128;
  int d  = m0 >> (8 + logT);
  int tl = (m0 >> 8) & (T - 1);
  int R0 = m0 & 255;                 // 0 or 128
  int n0 = blockIdx.y * 128;         // pack-col slice
  int lane = threadIdx.x & 63;
  int w = threadIdx.x >> 6;
  int wm = w >> 1, wn = w & 1;

  const int* x = (R0 >> 7) ? x2 : x1;
  int t = t0 + tl;
  int tpos = d ? (255 - t) : t;

  int ar  = lane >> 3;
  int acb = (lane & 7) * 16;
  int sw  = ar << 4;

  int toks[4];
  #pragma unroll
  for (int i = 0; i < 4; ++i) {
    int lrow = (i * 4 + w) * 8 + ar;
    toks[i] = x[((R0 + lrow) & 127) * 256 + tpos];
  }

  f32x4v acc[4][4] = {};
  const char* Bbase = (const char*)(wih_bf + (size_t)d * 1024 * EPAD);
  const char* Ebase = (const char*)embbf;

  for (int kt = 0; kt < 5; ++kt) {
    int k0b = kt * 128;
    #pragma unroll
    for (int i = 0; i < 4; ++i) {
      int lrow = (i * 4 + w) * 8 + ar;
      gload_lds16(Ebase + (size_t)toks[i] * 640 + k0b + (acb ^ sw),
                  (char*)As + (i * 4 + w) * 1024);
      gload_lds16(Bbase + (size_t)(n0 + lrow) * 640 + k0b + (acb ^ sw),
                  (char*)Bs + (i * 4 + w) * 1024);
    }
    __syncthreads();
    #pragma unroll
    for (int kc = 0; kc < 2; ++kc) {
      s16x8 a[4], b[4];
      int cb = kc * 64 + (lane >> 4) * 16;
      #pragma unroll
      for (int mf = 0; mf < 4; ++mf) {
        int rr = wm * 64 + mf * 16 + (lane & 15);
        a[mf] = *(const s16x8*)((const char*)As + rr * 128 + (cb ^ ((rr & 7) << 4)));
      }
      #pragma unroll
      for (int nf = 0; nf < 4; ++nf) {
        int rr = wn * 64 + nf * 16 + (lane & 15);
        b[nf] = *(const s16x8*)((const char*)Bs + rr * 128 + (cb ^ ((rr & 7) << 4)));
      }
      #pragma unroll
      for (int mf = 0; mf < 4; ++mf)
        #pragma unroll
        for (int nf = 0; nf < 4; ++nf)
          acc[mf][nf] = __builtin_amdgcn_mfma_f32_16x16x32_bf16(a[mf], b[nf], acc[mf][nf], 0, 0, 0);
    }
    __syncthreads();
  }

  float bv[4];
  #pragma unroll
  for (int nf = 0; nf < 4; ++nf)
    bv[nf] = bias[d * 1024 + n0 + wn * 64 + nf * 16 + (lane & 15)];

  // stage C (bf16, pack cols) into LDS
  #pragma unroll
  for (int mf = 0; mf < 4; ++mf)
    #pragma unroll
    for (int nf = 0; nf < 4; ++nf) {
      int col = wn * 64 + nf * 16 + (lane & 15);
      #pragma unroll
      for (int i = 0; i < 4; ++i) {
        int row = wm * 64 + mf * 16 + (lane >> 4) * 4 + i;
        smem[row * 128 + col] = f2bf(acc[mf][nf][i] + bv[nf]);
      }
    }
  __syncthreads();
  // store to [u][R][gate] layout: 16B chunk = 2 R x 4 gates, contiguous per u-run
  {
    u16* slab = ginc + (size_t)(d * T + tl) * 262144;
    int u0 = n0 >> 2;                 // 32 u per block
    int tid = threadIdx.x;
    #pragma unroll
    for (int it = 0; it < 8; ++it) {
      int ci = it * 256 + tid;        // 0..2047
      int u_loc = ci >> 6, c16 = ci & 63;
      int colb = (u_loc >> 2) * 16 + (u_loc & 3) * 4;
      s16x8 v;
      #pragma unroll
      for (int jj = 0; jj < 8; ++jj) {
        int Rl = c16 * 2 + (jj >> 2), g = jj & 3;
        v[jj] = (short)smem[Rl * 128 + colb + g];
      }
      *(s16x8*)(slab + ((size_t)(u0 + u_loc) * 256 + R0 + c16 * 2) * 4) = v;
    }
  }
}

// ---------------- recurrent bi-LSTM: 32 blocks = 2 dir x 16 stream-tiles (16 streams) ----------------
// Operand-swapped MFMA: A = Whh pack (register-resident i8), B = 16 h-streams (LDS, swizzled).
// Every lane gets all 4 gates of one (stream,u) cell in acc regs -> all-lane in-register gates.
// 16 waves, ONE lgkm-only barrier per step.
__global__ void __launch_bounds__(1024, 4)
lstm_chunk_kernel(const u16* __restrict__ ginc, const i32x4* __restrict__ wpk,
                  const float* __restrict__ swu, u32* hsave,
                  float* cstate, float* vaccst, float* vout,
                  const int* len1, const int* len2, int t0, int T)
{
  __shared__ __align__(16) char h_lds[2][16][256];   // [parity][stream][k], slot-XOR swizzled

  const int bid = blockIdx.x;        // 32
  const int d = bid >> 4, bt = bid & 15;
  const int R0 = bt * 16;
  const int tid = threadIdx.x;
  const int lane = tid & 63, w = tid >> 6;   // 16 waves; wave w owns u in [w*16, w*16+16)
  const int s = lane & 15, kg = lane >> 4;   // stream col, k-group / uh

  // A-frags (Whh i8) -> registers: 4 M-tiles x 4 K-tiles x 16B
  i32x4 afr[4][4];
  #pragma unroll
  for (int mi = 0; mi < 4; ++mi)
    #pragma unroll
    for (int kc = 0; kc < 4; ++kc)
      afr[mi][kc] = wpk[((size_t)(d * 64 + w * 4 + mi) * 4 + kc) * 64 + lane];
  float swl[4];
  #pragma unroll
  for (int mi = 0; mi < 4; ++mi)
    swl[mi] = swu[d * 256 + w * 16 + mi * 4 + kg];

  // init h (both parities zeroed; restore chunk state into [0])
  ((u32*)h_lds)[tid * 2] = 0u;
  ((u32*)h_lds)[tid * 2 + 1] = 0u;
  __syncthreads();
  if (t0 > 0) ((u32*)h_lds[0])[tid] = hsave[bid * 1024 + tid];

  const int R = R0 + s;
  int lm = ((R >> 7) ? len2 : len1)[R & 127] - 1;
  float c[4] = {0.f, 0.f, 0.f, 0.f}, va[4] = {0.f, 0.f, 0.f, 0.f};
  if (t0 > 0) {
    #pragma unroll
    for (int mi = 0; mi < 4; ++mi) {
      int u = w * 16 + mi * 4 + kg;
      size_t sidx = ((size_t)d * 256 + R) * 256 + u;
      c[mi] = cstate[sidx];
      va[mi] = vaccst[sidx];
    }
  }

  // gin: slab (d,tl) = [u][R][g4]; per-lane u16x4 at ((u*256 + R)*4)
  const u16* g0 = ginc + (size_t)d * T * 262144;
  u16x4 gv[4];
  #pragma unroll
  for (int mi = 0; mi < 4; ++mi)
    gv[mi] = *(const u16x4*)(g0 + ((size_t)(w * 16 + mi * 4 + kg) * 256 + R) * 4);
  __syncthreads();

  const bool final_chunk = (t0 + T == 256);
  int par = 0;

  for (int tl = 0; tl < T; ++tl) {
    // prefetch next step's gates (fly across the barrier)
    const u16* gn = g0 + (size_t)((tl + 1 < T) ? tl + 1 : tl) * 262144;
    u16x4 gvn[4];
    #pragma unroll
    for (int mi = 0; mi < 4; ++mi)
      gvn[mi] = *(const u16x4*)(gn + ((size_t)(w * 16 + mi * 4 + kg) * 256 + R) * 4);

    // B-frags from swizzled h: lane reads 16B of stream s at slot (kc*4+kg)^s
    i32x4 bf[4];
    #pragma unroll
    for (int kc = 0; kc < 4; ++kc)
      bf[kc] = *(const i32x4*)&h_lds[par][s][(((kc * 4 + kg) ^ s) << 4)];

    i32x4 acc[4];
    #pragma unroll
    for (int mi = 0; mi < 4; ++mi) {
      i32x4 z = {0, 0, 0, 0};
      #pragma unroll
      for (int kc = 0; kc < 4; ++kc)
        z = __builtin_amdgcn_mfma_i32_16x16x64_i8(afr[mi][kc], bf[kc], z, 0, 0, 0);
      acc[mi] = z;
    }

    // all-lane gate math: lane's cell per M-tile = (stream s, u = w*16+mi*4+kg), gates in regs
    int tmap = d ? (255 - (t0 + tl)) : (t0 + tl);
    bool keep = tmap < lm;
    #pragma unroll
    for (int mi = 0; mi < 4; ++mi) {
      float si = (float)acc[mi][0] * swl[mi] + bf2f(gv[mi][0]);
      float sf = (float)acc[mi][1] * swl[mi] + bf2f(gv[mi][1]);
      float sg = (float)acc[mi][2] * swl[mi] + bf2f(gv[mi][2]);
      float so = (float)acc[mi][3] * swl[mi] + bf2f(gv[mi][3]);
      float I = __builtin_amdgcn_rcpf(1.f + __expf(-si));
      float F = __builtin_amdgcn_rcpf(1.f + __expf(-sf));
      float G = 1.f - 2.f * __builtin_amdgcn_rcpf(__expf(2.f * sg) + 1.f);
      float O = __builtin_amdgcn_rcpf(1.f + __expf(-so));
      float cn = F * c[mi] + I * G;
      c[mi] = cn;
      float hn = O * (1.f - 2.f * __builtin_amdgcn_rcpf(__expf(2.f * cn) + 1.f));
      if (keep) va[mi] += hn;
      int q = (int)rintf(hn * 127.f);
      // u>>4 == w, u&15 == mi*4+kg -> slot (w^s), byte mi*4+kg
      h_lds[par ^ 1][s][((w ^ s) << 4) + mi * 4 + kg] = (char)q;
    }
    lds_barrier();
    #pragma unroll
    for (int mi = 0; mi < 4; ++mi) gv[mi] = gvn[mi];
    par ^= 1;
  }

  #pragma unroll
  for (int mi = 0; mi < 4; ++mi) {
    int u = w * 16 + mi * 4 + kg;
    size_t sidx = ((size_t)d * 256 + R) * 256 + u;
    cstate[sidx] = c[mi];
    vaccst[sidx] = va[mi];
    if (final_chunk)
      vout[((size_t)(R >> 7) * 128 + (R & 127)) * 512 + d * 256 + u] = va[mi] / (float)lm;
  }
  if (!final_chunk) hsave[bid * 1024 + tid] = ((u32*)h_lds[par])[tid];
}

// ---------------- MLP head ----------------
__global__ void mlp_kernel(const float* v, const float* W1, const float* b1,
                           const float* W2, const float* b2, const float* Wo, const float* bo,
                           float* out)
{
  __shared__ float vec[512];
  __shared__ float a1[512];
  __shared__ float red[4];
  int b = blockIdx.x;
  int tid = threadIdx.x;   // 256
  for (int i = tid; i < 512; i += 256)
    vec[i] = fabsf(v[(size_t)b * 512 + i] - v[(size_t)(128 + b) * 512 + i]);
  __syncthreads();
  for (int j = tid; j < 512; j += 256) {
    float s = b1[j];
    const float* wr = W1 + (size_t)j * 512;
    for (int k = 0; k < 512; ++k) s += vec[k] * wr[k];
    a1[j] = fmaxf(s, 0.f);
  }
  __syncthreads();
  float s = b2[tid];
  {
    const float* wr = W2 + (size_t)tid * 512;
    for (int k = 0; k < 512; ++k) s += a1[k] * wr[k];
  }
  float p = fmaxf(s, 0.f) * Wo[tid];
  for (int off = 32; off > 0; off >>= 1) p += __shfl_down(p, off);
  if ((tid & 63) == 0) red[tid >> 6] = p;
  __syncthreads();
  if (tid == 0) {
    float logit = red[0] + red[1] + red[2] + red[3] + bo[0];
    out[b] = logit;
    out[128 + b] = 1.f / (1.f + __expf(-logit));
  }
}

extern "C" void kernel_launch(void* const* d_in, const int* in_sizes, int n_in,
                              void* d_out, int out_size, void* d_ws, size_t ws_size,
                              hipStream_t stream)
{
  const int*   x1    = (const int*)d_in[0];
  const int*   x2    = (const int*)d_in[1];
  const int*   len1  = (const int*)d_in[2];
  const int*   len2  = (const int*)d_in[3];
  const float* emb   = (const float*)d_in[4];
  const float* wih_f = (const float*)d_in[5];
  const float* whh_f = (const float*)d_in[6];
  const float* bih_f = (const float*)d_in[7];
  const float* bhh_f = (const float*)d_in[8];
  const float* wih_b = (const float*)d_in[9];
  const float* whh_b = (const float*)d_in[10];
  const float* bih_b = (const float*)d_in[11];
  const float* bhh_b = (const float*)d_in[12];
  const float* W1    = (const float*)d_in[13];
  const float* b1    = (const float*)d_in[14];
  const float* W2    = (const float*)d_in[15];
  const float* b2    = (const float*)d_in[16];
  const float* Wo    = (const float*)d_in[17];
  const float* bo    = (const float*)d_in[18];

  char* p = (char*)d_ws;
  u16*   wih_bf = (u16*)p;          p += SZ_WIH;
  char*  wpk    = (char*)p;         p += SZ_WPK;
  float* swp    = (float*)p;        p += SZ_SW;
  float* bias   = (float*)p;        p += SZ_BIAS;
  u32*   hsave  = (u32*)p;          p += SZ_HSV;
  float* cst    = (float*)p;        p += SZ_CST;
  float* vac    = (float*)p;        p += SZ_VAC;
  float* vout   = (float*)p;        p += SZ_VOUT;
  u16*   embbf  = (u16*)p;          p += SZ_EMB;

  int T = 256;
  while (T > 1 && FIXED_B + (size_t)T * PER_T > ws_size) T >>= 1;
  int logT = __builtin_ctz((unsigned)T);
  u16* ginc = (u16*)p;              // [d][tl][u 256][R 256][g 4] u16

  {
    int total = 2 * 1024 * EPAD + 2 * 1024;
    prep_kernel<<<(total + 255) / 256, 256, 0, stream>>>(
        wih_f, bih_f, bhh_f, wih_b, bih_b, bhh_b, wih_bf, bias);
  }
  whhq_kernel<<<512, 64, 0, stream>>>(whh_f, whh_b, wpk, swp);
  embconv_kernel<<<VOCAB, EPAD, 0, stream>>>(emb, embbf);

  int nch = 256 / T;
  for (int ch = 0; ch < nch; ++ch) {
    int tt0 = ch * T;
    gemm_chunk_kernel<<<dim3(4 * T, 8), 256, 0, stream>>>(x1, x2, embbf, wih_bf, bias,
                                                          ginc, tt0, T, logT);
    lstm_chunk_kernel<<<32, 1024, 0, stream>>>(ginc, (const i32x4*)wpk, swp, hsave,
                                               cst, vac, vout, len1, len2, tt0, T);
  }

  mlp_kernel<<<128, 256, 0, stream>>>(vout, W1, b1, W2, b2, Wo, bo, (float*)d_out);
}

// Round 10
// 649.241 us; speedup vs baseline: 1.1250x; 1.1057x over previous
//
#include <hip/hip_runtime.h>
#include <hip/hip_bf16.h>
#include <math.h>

typedef unsigned short u16;
typedef short s16x8 __attribute__((ext_vector_type(8)));
typedef float f32x4v __attribute__((ext_vector_type(4)));
typedef int i32x4 __attribute__((ext_vector_type(4)));
typedef unsigned short u16x4 __attribute__((ext_vector_type(4)));

#define EDIM 300
#define EPAD 320
#define VOCAB 50000
#define LOG2E 1.44269504f

// ---- fixed workspace layout (bytes) ----
static constexpr size_t SZ_WIH  = (size_t)2 * 1024 * EPAD * 2;   // bf16 [2][1024 pack][320]
static constexpr size_t SZ_WPK  = (size_t)2 * 1024 * 256;        // i8 packed Whh frags
static constexpr size_t SZ_SW   = (size_t)2 * 1024 * 4;          // f32 per-row scale (pack order, xLOG2E)
static constexpr size_t SZ_BIAS = (size_t)2 * 1024 * 4;          // f32 (pack order)
static constexpr size_t SZ_HSV  = (size_t)2 * 256 * 256;         // i8 h chunk-boundary save
static constexpr size_t SZ_CST  = (size_t)2 * 256 * 256 * 4;     // f32 c-state
static constexpr size_t SZ_VAC  = (size_t)2 * 256 * 256 * 4;     // f32 vacc-state
static constexpr size_t SZ_VOUT = (size_t)2 * 128 * 512 * 4;     // f32 [2][128][512]
static constexpr size_t SZ_EMB  = (size_t)VOCAB * EPAD * 2;      // bf16 emb table padded (32 MB)
static constexpr size_t FIXED_B = SZ_WIH + SZ_WPK + SZ_SW + SZ_BIAS + SZ_HSV + SZ_CST + SZ_VAC + SZ_VOUT + SZ_EMB;
static constexpr size_t PER_T   = (size_t)512 * 1024 * 2;        // ginc per step (1 MB)

// pack permutation: pack p = w*128 + q*16 + ul  (w=wave 0..7, q=uh*4+gate, ul 0..15)
//   -> logical Whh/Wih row jlog = (q&3)*256 + w*32 + (q>>2)*16 + ul
// sigma (ginc column) s = w*128 + uh*64 + ul*4 + gate  (gates contiguous per cell)

__device__ __forceinline__ float bf2f(u16 u) {
  union { float f; unsigned int i; } v; v.i = ((unsigned int)u) << 16; return v.f;
}
__device__ __forceinline__ u16 f2bf(float f) {
  union { float f; unsigned int i; } v; v.f = f;
  unsigned int r = v.i + 0x7fffu + ((v.i >> 16) & 1u);   // RNE (finite inputs)
  return (u16)(r >> 16);
}
__device__ __forceinline__ void gload_lds16(const void* g, void* l) {
  __builtin_amdgcn_global_load_lds((const __attribute__((address_space(1))) void*)g,
                                   (__attribute__((address_space(3))) void*)l, 16, 0, 0);
}
// order LDS ops across waves WITHOUT draining vmcnt
__device__ __forceinline__ void lds_barrier() {
  asm volatile("s_waitcnt lgkmcnt(0)" ::: "memory");
  __builtin_amdgcn_s_barrier();
}

// ---------------- prep: Wih->bf16 padded (pack-row order), bias sum (pack order) ----------------
__global__ void prep_kernel(const float* wih_f, const float* bih_f, const float* bhh_f,
                            const float* wih_b, const float* bih_b, const float* bhh_b,
                            u16* wih_bf, float* bias)
{
  int tid = blockIdx.x * blockDim.x + threadIdx.x;
  if (tid < 2 * 1024 * EPAD) {
    int d = tid / (1024 * EPAD); int rr = tid % (1024 * EPAD);
    int p = rr / EPAD; int k = rr % EPAD;
    int w = p >> 7, q = (p >> 4) & 7, ul = p & 15;
    int jlog = (q & 3) * 256 + w * 32 + (q >> 2) * 16 + ul;
    const float* wsrc = d ? wih_b : wih_f;
    wih_bf[tid] = (k < EDIM) ? f2bf(wsrc[(size_t)jlog * EDIM + k]) : (u16)0;
  }
  int t2 = tid - 2 * 1024 * EPAD;
  if (t2 >= 0 && t2 < 2 * 1024) {
    int d = t2 >> 10; int p = t2 & 1023;
    int w = p >> 7, q = (p >> 4) & 7, ul = p & 15;
    int jlog = (q & 3) * 256 + w * 32 + (q >> 2) * 16 + ul;
    bias[t2] = d ? (bih_b[jlog] + bhh_b[jlog]) : (bih_f[jlog] + bhh_f[jlog]);
  }
}

// ---------------- emb -> bf16, K padded 300->320 (one-time) ----------------
__global__ void embconv_kernel(const float* emb, u16* embbf)
{
  int r = blockIdx.x;
  int k = threadIdx.x;     // 320
  embbf[(size_t)r * EPAD + k] = (k < EDIM) ? f2bf(emb[(size_t)r * EDIM + k]) : (u16)0;
}

// ---------------- Whh -> i8 quant + MFMA-fragment pack (8-wave pack order) ----------------
__global__ void whhq_kernel(const float* whh_f, const float* whh_b, char* wpk, float* sw)
{
  int jp = blockIdx.x;             // 0..2047 = d*1024 + pack p
  int t = threadIdx.x;             // 64
  int d = jp >> 10, p = jp & 1023;
  int w = p >> 7, q = (p >> 4) & 7, ul = p & 15;
  int jlog = (q & 3) * 256 + w * 32 + (q >> 2) * 16 + ul;
  const float* src = (d ? whh_b : whh_f) + (size_t)jlog * 256;
  float v[4]; float m = 0.f;
  #pragma unroll
  for (int kk = 0; kk < 4; ++kk) { v[kk] = src[t * 4 + kk]; m = fmaxf(m, fabsf(v[kk])); }
  #pragma unroll
  for (int off = 32; off > 0; off >>= 1) m = fmaxf(m, __shfl_xor(m, off));
  float sunit = m / 127.f;
  if (sunit < 1e-30f) sunit = 1e-30f;
  unsigned int pk = 0;
  #pragma unroll
  for (int kk = 0; kk < 4; ++kk) {
    int qv = (int)rintf(v[kk] / sunit);
    qv = qv > 127 ? 127 : (qv < -127 ? -127 : qv);
    pk |= ((unsigned int)(qv & 255)) << (8 * kk);
  }
  // frag entry (d,w,q,kc,lane=kg*16+ul): bytes = Wq[jlog][kc*64+kg*16 .. +16)
  size_t base = ((((size_t)(d * 8 + w) * 8 + q) * 4 + (t >> 4)) * 64
                 + (((t >> 2) & 3) * 16 + ul)) * 16 + (t & 3) * 4;
  *(unsigned int*)&wpk[base] = pk;
  if (t == 0) sw[jp] = sunit / 127.f * LOG2E;   // exp2-domain scale
}

// ---------------- fused gather + input projection GEMM, full-N per block ----------------
// Block = 128 M-rows x full N=1024. A (token gather) staged ONCE full-K in 80KB LDS;
// B double-buffered 2x16KB from L2. Epilogue: direct sigma-permuted u16x4 stores
// (for a 128-col slice: uh=wn, gate=nf, ul=lane&15 -> 4 gates of one cell per thread).
__global__ void __launch_bounds__(256, 1)
gemm_chunk_kernel(const int* __restrict__ x1, const int* __restrict__ x2,
                  const u16* __restrict__ embbf, const u16* __restrict__ wih_bf,
                  const float* __restrict__ bias, u16* __restrict__ ginc,
                  int t0, int T, int logT)
{
  __shared__ __align__(16) u16 As[5 * 8192];    // 80KB: [kt][16 grp][1024B]
  __shared__ __align__(16) u16 Bs[2 * 8192];    // 32KB double buffer

  int m0 = blockIdx.x * 128;
  int d  = m0 >> (8 + logT);
  int tl = (m0 >> 8) & (T - 1);
  int R0 = m0 & 255;                 // 0 or 128
  int lane = threadIdx.x & 63;
  int w = threadIdx.x >> 6;          // 4 waves
  int wm = w >> 1, wn = w & 1;

  const int* x = (R0 >> 7) ? x2 : x1;
  int t = t0 + tl;
  int tpos = d ? (255 - t) : t;

  int ar  = lane >> 3;               // row within 8-row stripe
  int acb = (lane & 7) * 16;         // byte col (16B slot)
  int swz = ar << 4;

  int toks[4];
  #pragma unroll
  for (int i = 0; i < 4; ++i) {
    int lrow = (i * 4 + w) * 8 + ar;
    toks[i] = x[((R0 + lrow) & 127) * 256 + tpos];
  }

  const char* Bbase = (const char*)(wih_bf + (size_t)d * 1024 * EPAD);
  const char* Ebase = (const char*)embbf;

  // stage full-K A (once) + B(nt=0, kt=0) into buf 0
  #pragma unroll
  for (int kt = 0; kt < 5; ++kt)
    #pragma unroll
    for (int i = 0; i < 4; ++i)
      gload_lds16(Ebase + (size_t)toks[i] * 640 + kt * 128 + (acb ^ swz),
                  (char*)As + kt * 16384 + (i * 4 + w) * 1024);
  #pragma unroll
  for (int i = 0; i < 4; ++i) {
    int lrow = (i * 4 + w) * 8 + ar;
    gload_lds16(Bbase + (size_t)lrow * 640 + (acb ^ swz),
                (char*)Bs + (i * 4 + w) * 1024);
  }
  __syncthreads();

  size_t rowbase = (size_t)(d * T + tl) * 256 + R0;
  int buf = 0;

  for (int nt = 0; nt < 8; ++nt) {
    f32x4v acc[4][4] = {};
    for (int kt = 0; kt < 5; ++kt) {
      // prefetch next B tile into buf^1
      int nkt = kt + 1, nnt = nt;
      if (nkt == 5) { nkt = 0; nnt = nt + 1; }
      if (nnt < 8) {
        #pragma unroll
        for (int i = 0; i < 4; ++i) {
          int lrow = nnt * 128 + (i * 4 + w) * 8 + ar;
          gload_lds16(Bbase + (size_t)lrow * 640 + nkt * 128 + (acb ^ swz),
                      (char*)Bs + (buf ^ 1) * 16384 + (i * 4 + w) * 1024);
        }
      }
      // compute As[kt] x Bs[buf]
      #pragma unroll
      for (int kc = 0; kc < 2; ++kc) {
        s16x8 a[4], b[4];
        int cb = kc * 64 + (lane >> 4) * 16;
        #pragma unroll
        for (int mf = 0; mf < 4; ++mf) {
          int rr = wm * 64 + mf * 16 + (lane & 15);
          a[mf] = *(const s16x8*)((const char*)As + kt * 16384 + rr * 128 + (cb ^ ((rr & 7) << 4)));
        }
        #pragma unroll
        for (int nf = 0; nf < 4; ++nf) {
          int rr = wn * 64 + nf * 16 + (lane & 15);
          b[nf] = *(const s16x8*)((const char*)Bs + buf * 16384 + rr * 128 + (cb ^ ((rr & 7) << 4)));
        }
        #pragma unroll
        for (int mf = 0; mf < 4; ++mf)
          #pragma unroll
          for (int nf = 0; nf < 4; ++nf)
            acc[mf][nf] = __builtin_amdgcn_mfma_f32_16x16x32_bf16(a[mf], b[nf], acc[mf][nf], 0, 0, 0);
      }
      __syncthreads();
      buf ^= 1;
    }

    // epilogue nt: bias + LOG2E fold, direct sigma store (u16x4 = 4 gates of one cell)
    float bv[4];
    #pragma unroll
    for (int nf = 0; nf < 4; ++nf)
      bv[nf] = bias[d * 1024 + nt * 128 + wn * 64 + nf * 16 + (lane & 15)];
    int scol = nt * 128 + wn * 64 + (lane & 15) * 4;
    #pragma unroll
    for (int mf = 0; mf < 4; ++mf)
      #pragma unroll
      for (int i = 0; i < 4; ++i) {
        int row = wm * 64 + mf * 16 + (lane >> 4) * 4 + i;
        u16x4 v;
        #pragma unroll
        for (int nf = 0; nf < 4; ++nf)
          v[nf] = f2bf((acc[mf][nf][i] + bv[nf]) * LOG2E);
        *(u16x4*)(ginc + (rowbase + row) * 1024 + scol) = v;
      }
  }
}

// ---------------- recurrent bi-LSTM (R7 structure + exp2-domain gates) ----------------
// 256 blocks = 2 dir x 128 two-row tiles; 8 waves; wave w owns u in [w*32,(w+1)*32) x 4 gates.
// ONE lgkm-only barrier per step; h double-buffered in LDS.
__global__ void __launch_bounds__(512)
lstm_chunk_kernel(const u16* __restrict__ ginc, const i32x4* __restrict__ wpk,
                  const float* __restrict__ sw, char* hsave,
                  float* cstate, float* vaccst, float* vout,
                  const int* len1, const int* len2, int t0, int T)
{
  __shared__ __align__(16) char h_lds[2][2][288];   // [parity][row][256 k +pad]

  const int bid = blockIdx.x;
  const int d = bid >> 7, bt = bid & 127;
  const int tid = threadIdx.x;
  const int lane = tid & 63, w = tid >> 6;          // 8 waves
  const int cl = lane & 15;

  // Whh i8 fragments -> registers; per-column scales (pack order, already xLOG2E)
  i32x4 bfr[8][4];
  #pragma unroll
  for (int q = 0; q < 8; ++q)
    #pragma unroll
    for (int kc = 0; kc < 4; ++kc)
      bfr[q][kc] = wpk[(((size_t)(d * 8 + w) * 8 + q) * 4 + kc) * 64 + lane];
  float swl[8];
  #pragma unroll
  for (int q = 0; q < 8; ++q)
    swl[q] = sw[d * 1024 + w * 128 + q * 16 + cl];

  const int R0 = bt * 2;
  {
    int r = tid >> 8, u = tid & 255;
    h_lds[0][r][u] = (t0 > 0) ? hsave[((size_t)d * 256 + R0 + r) * 256 + u] : (char)0;
  }

  int lm0 = ((R0 >> 7) ? len2 : len1)[R0 & 127] - 1;
  int lm1 = (((R0 + 1) >> 7) ? len2 : len1)[(R0 + 1) & 127] - 1;

  const bool gl = (lane < 16);
  float c[2][2] = {{0.f,0.f},{0.f,0.f}}, va[2][2] = {{0.f,0.f},{0.f,0.f}};
  if (t0 > 0 && gl) {
    #pragma unroll
    for (int r = 0; r < 2; ++r)
      #pragma unroll
      for (int uh = 0; uh < 2; ++uh) {
        size_t sidx = ((size_t)d * 256 + R0 + r) * 256 + (w * 32 + uh * 16 + cl);
        c[r][uh] = cstate[sidx];
        va[r][uh] = vaccst[sidx];
      }
  }

  const size_t GSTEP = (size_t)256 * 1024;
  const u16* gbase = ginc + ((size_t)d * T * 256 + R0) * 1024;
  u16x4 gv[2][2];
  if (gl) {
    #pragma unroll
    for (int r = 0; r < 2; ++r)
      #pragma unroll
      for (int uh = 0; uh < 2; ++uh)
        gv[r][uh] = *(const u16x4*)(gbase + (size_t)r * 1024 + w * 128 + uh * 64 + cl * 4);
  }
  __syncthreads();

  const bool final_chunk = (t0 + T == 256);
  int par = 0;

  for (int tl = 0; tl < T; ++tl) {
    // prefetch next step's gates (stays in flight across the barrier)
    const u16* gnb = gbase + GSTEP * (size_t)((tl + 1 < T) ? tl + 1 : tl);
    u16x4 gvn[2][2];
    if (gl) {
      #pragma unroll
      for (int r = 0; r < 2; ++r)
        #pragma unroll
        for (int uh = 0; uh < 2; ++uh)
          gvn[r][uh] = *(const u16x4*)(gnb + (size_t)r * 1024 + w * 128 + uh * 64 + cl * 4);
    }

    // A-frags (rows 0,1 real; others zero)
    i32x4 a[4] = {{0,0,0,0},{0,0,0,0},{0,0,0,0},{0,0,0,0}};
    if (cl < 2) {
      #pragma unroll
      for (int kc = 0; kc < 4; ++kc)
        a[kc] = *(const i32x4*)&h_lds[par][cl][kc * 64 + (lane >> 4) * 16];
    }
    i32x4 acc[8];
    #pragma unroll
    for (int q = 0; q < 8; ++q) {
      i32x4 z = {0, 0, 0, 0};
      #pragma unroll
      for (int kc = 0; kc < 4; ++kc)
        z = __builtin_amdgcn_mfma_i32_16x16x64_i8(a[kc], bfr[q][kc], z, 0, 0, 0);
      acc[q] = z;
    }

    // in-register gate math on lanes 0..15 (cells: 2 rows x 2 uh) — exp2 domain
    if (gl) {
      int tmap = d ? (255 - (t0 + tl)) : (t0 + tl);
      #pragma unroll
      for (int r = 0; r < 2; ++r) {
        int lm = r ? lm1 : lm0;
        #pragma unroll
        for (int uh = 0; uh < 2; ++uh) {
          float s0 = (float)acc[uh * 4 + 0][r] * swl[uh * 4 + 0] + bf2f(gv[r][uh][0]);
          float s1 = (float)acc[uh * 4 + 1][r] * swl[uh * 4 + 1] + bf2f(gv[r][uh][1]);
          float s2 = (float)acc[uh * 4 + 2][r] * swl[uh * 4 + 2] + bf2f(gv[r][uh][2]);
          float s3 = (float)acc[uh * 4 + 3][r] * swl[uh * 4 + 3] + bf2f(gv[r][uh][3]);
          float I = __builtin_amdgcn_rcpf(1.f + exp2f(-s0));
          float F = __builtin_amdgcn_rcpf(1.f + exp2f(-s1));
          float G = 1.f - 2.f * __builtin_amdgcn_rcpf(exp2f(s2 + s2) + 1.f);
          float O = __builtin_amdgcn_rcpf(1.f + exp2f(-s3));
          float cn = F * c[r][uh] + I * G;
          c[r][uh] = cn;
          float hn = O * (1.f - 2.f * __builtin_amdgcn_rcpf(exp2f(cn * 2.88539008f) + 1.f));
          if (tmap < lm) va[r][uh] += hn;
          h_lds[par ^ 1][r][w * 32 + uh * 16 + cl] = (char)(int)rintf(hn * 127.f);
        }
      }
    }
    lds_barrier();
    #pragma unroll
    for (int r = 0; r < 2; ++r)
      #pragma unroll
      for (int uh = 0; uh < 2; ++uh)
        gv[r][uh] = gvn[r][uh];
    par ^= 1;
  }

  if (gl) {
    #pragma unroll
    for (int r = 0; r < 2; ++r) {
      int lm = r ? lm1 : lm0;
      #pragma unroll
      for (int uh = 0; uh < 2; ++uh) {
        int u = w * 32 + uh * 16 + cl;
        size_t sidx = ((size_t)d * 256 + R0 + r) * 256 + u;
        cstate[sidx] = c[r][uh];
        vaccst[sidx] = va[r][uh];
        if (final_chunk) {
          int RR = R0 + r;
          vout[((size_t)(RR >> 7) * 128 + (RR & 127)) * 512 + d * 256 + u] = va[r][uh] / (float)lm;
        }
      }
    }
  }
  if (!final_chunk) {
    int r = tid >> 8, u = tid & 255;
    hsave[((size_t)d * 256 + R0 + r) * 256 + u] = h_lds[par][r][u];
  }
}

// ---------------- MLP head ----------------
__global__ void mlp_kernel(const float* v, const float* W1, const float* b1,
                           const float* W2, const float* b2, const float* Wo, const float* bo,
                           float* out)
{
  __shared__ float vec[512];
  __shared__ float a1[512];
  __shared__ float red[4];
  int b = blockIdx.x;
  int tid = threadIdx.x;   // 256
  for (int i = tid; i < 512; i += 256)
    vec[i] = fabsf(v[(size_t)b * 512 + i] - v[(size_t)(128 + b) * 512 + i]);
  __syncthreads();
  for (int j = tid; j < 512; j += 256) {
    float s = b1[j];
    const float* wr = W1 + (size_t)j * 512;
    for (int k = 0; k < 512; ++k) s += vec[k] * wr[k];
    a1[j] = fmaxf(s, 0.f);
  }
  __syncthreads();
  float s = b2[tid];
  {
    const float* wr = W2 + (size_t)tid * 512;
    for (int k = 0; k < 512; ++k) s += a1[k] * wr[k];
  }
  float p = fmaxf(s, 0.f) * Wo[tid];
  for (int off = 32; off > 0; off >>= 1) p += __shfl_down(p, off);
  if ((tid & 63) == 0) red[tid >> 6] = p;
  __syncthreads();
  if (tid == 0) {
    float logit = red[0] + red[1] + red[2] + red[3] + bo[0];
    out[b] = logit;
    out[128 + b] = 1.f / (1.f + __expf(-logit));
  }
}

extern "C" void kernel_launch(void* const* d_in, const int* in_sizes, int n_in,
                              void* d_out, int out_size, void* d_ws, size_t ws_size,
                              hipStream_t stream)
{
  const int*   x1    = (const int*)d_in[0];
  const int*   x2    = (const int*)d_in[1];
  const int*   len1  = (const int*)d_in[2];
  const int*   len2  = (const int*)d_in[3];
  const float* emb   = (const float*)d_in[4];
  const float* wih_f = (const float*)d_in[5];
  const float* whh_f = (const float*)d_in[6];
  const float* bih_f = (const float*)d_in[7];
  const float* bhh_f = (const float*)d_in[8];
  const float* wih_b = (const float*)d_in[9];
  const float* whh_b = (const float*)d_in[10];
  const float* bih_b = (const float*)d_in[11];
  const float* bhh_b = (const float*)d_in[12];
  const float* W1    = (const float*)d_in[13];
  const float* b1    = (const float*)d_in[14];
  const float* W2    = (const float*)d_in[15];
  const float* b2    = (const float*)d_in[16];
  const float* Wo    = (const float*)d_in[17];
  const float* bo    = (const float*)d_in[18];

  char* p = (char*)d_ws;
  u16*   wih_bf = (u16*)p;          p += SZ_WIH;
  char*  wpk    = (char*)p;         p += SZ_WPK;
  float* swp    = (float*)p;        p += SZ_SW;
  float* bias   = (float*)p;        p += SZ_BIAS;
  char*  hsave  = (char*)p;         p += SZ_HSV;
  float* cst    = (float*)p;        p += SZ_CST;
  float* vac    = (float*)p;        p += SZ_VAC;
  float* vout   = (float*)p;        p += SZ_VOUT;
  u16*   embbf  = (u16*)p;          p += SZ_EMB;

  int T = 256;
  while (T > 1 && FIXED_B + (size_t)T * PER_T > ws_size) T >>= 1;
  int logT = __builtin_ctz((unsigned)T);
  u16* ginc = (u16*)p;              // [(d*T+tl)*256 + R][1024 sigma-cols] u16

  {
    int total = 2 * 1024 * EPAD + 2 * 1024;
    prep_kernel<<<(total + 255) / 256, 256, 0, stream>>>(
        wih_f, bih_f, bhh_f, wih_b, bih_b, bhh_b, wih_bf, bias);
  }
  whhq_kernel<<<2048, 64, 0, stream>>>(whh_f, whh_b, wpk, swp);
  embconv_kernel<<<VOCAB, EPAD, 0, stream>>>(emb, embbf);

  int nch = 256 / T;
  for (int ch = 0; ch < nch; ++ch) {
    int tt0 = ch * T;
    gemm_chunk_kernel<<<dim3(4 * T), 256, 0, stream>>>(x1, x2, embbf, wih_bf, bias,
                                                       ginc, tt0, T, logT);
    lstm_chunk_kernel<<<256, 512, 0, stream>>>(ginc, (const i32x4*)wpk, swp, hsave,
                                               cst, vac, vout, len1, len2, tt0, T);
  }

  mlp_kernel<<<128, 256, 0, stream>>>(vout, W1, b1, W2, b2, Wo, bo, (float*)d_out);
}

// Round 11
// 586.196 us; speedup vs baseline: 1.2460x; 1.1075x over previous
//
#include <hip/hip_runtime.h>
#include <hip/hip_bf16.h>
#include <math.h>

typedef unsigned short u16;
typedef short s16x8 __attribute__((ext_vector_type(8)));
typedef float f32x4v __attribute__((ext_vector_type(4)));
typedef int i32x4 __attribute__((ext_vector_type(4)));
typedef unsigned short u16x4 __attribute__((ext_vector_type(4)));

#define EDIM 300
#define EPAD 320
#define VOCAB 50000

// ---- fixed workspace layout (bytes) ----
static constexpr size_t SZ_WIH  = (size_t)2 * 1024 * EPAD * 2;   // bf16 [2][1024 pack][320]
static constexpr size_t SZ_WPK  = (size_t)2 * 1024 * 256;        // i8 packed Whh frags
static constexpr size_t SZ_SW   = (size_t)2 * 1024 * 4;          // f32 per-row scale (pack order)
static constexpr size_t SZ_BIAS = (size_t)2 * 1024 * 4;          // f32 (pack order)
static constexpr size_t SZ_HSV  = (size_t)2 * 256 * 256;         // i8 h chunk-boundary save
static constexpr size_t SZ_CST  = (size_t)2 * 256 * 256 * 4;     // f32 c-state
static constexpr size_t SZ_VAC  = (size_t)2 * 256 * 256 * 4;     // f32 vacc-state
static constexpr size_t SZ_VOUT = (size_t)2 * 128 * 512 * 4;     // f32 [2][128][512]
static constexpr size_t SZ_EMB  = (size_t)VOCAB * EPAD * 2;      // bf16 emb table padded (32 MB)
static constexpr size_t SZ_PAD  = (size_t)512 * 1024;            // +1 slab: unclamped prefetch
static constexpr size_t FIXED_B = SZ_WIH + SZ_WPK + SZ_SW + SZ_BIAS + SZ_HSV + SZ_CST + SZ_VAC + SZ_VOUT + SZ_EMB + SZ_PAD;
static constexpr size_t PER_T   = (size_t)512 * 1024 * 2;        // ginc per step (1 MB, both dirs)

// pack permutation: pack p = w*128 + q*16 + ul  (w=wave 0..7, q=uh*4+gate, ul 0..15)
//   -> logical Whh/Wih row jlog = (q&3)*256 + w*32 + (q>>2)*16 + ul
// sigma (ginc column) s = w*128 + uh*64 + ul*4 + gate  (gates contiguous per cell)

__device__ __forceinline__ float bf2f(u16 u) {
  union { float f; unsigned int i; } v; v.i = ((unsigned int)u) << 16; return v.f;
}
__device__ __forceinline__ u16 f2bf(float f) {
  union { float f; unsigned int i; } v; v.f = f;
  unsigned int r = v.i + 0x7fffu + ((v.i >> 16) & 1u);   // RNE (finite inputs)
  return (u16)(r >> 16);
}
__device__ __forceinline__ void gload_lds16(const void* g, void* l) {
  __builtin_amdgcn_global_load_lds((const __attribute__((address_space(1))) void*)g,
                                   (__attribute__((address_space(3))) void*)l, 16, 0, 0);
}
// order LDS ops across waves WITHOUT draining vmcnt
__device__ __forceinline__ void lds_barrier() {
  asm volatile("s_waitcnt lgkmcnt(0)" ::: "memory");
  __builtin_amdgcn_s_barrier();
}

// ---------------- prep: Wih->bf16 padded (pack-row order), bias sum (pack order) ----------------
__global__ void prep_kernel(const float* wih_f, const float* bih_f, const float* bhh_f,
                            const float* wih_b, const float* bih_b, const float* bhh_b,
                            u16* wih_bf, float* bias)
{
  int tid = blockIdx.x * blockDim.x + threadIdx.x;
  if (tid < 2 * 1024 * EPAD) {
    int d = tid / (1024 * EPAD); int rr = tid % (1024 * EPAD);
    int p = rr / EPAD; int k = rr % EPAD;
    int w = p >> 7, q = (p >> 4) & 7, ul = p & 15;
    int jlog = (q & 3) * 256 + w * 32 + (q >> 2) * 16 + ul;
    const float* wsrc = d ? wih_b : wih_f;
    wih_bf[tid] = (k < EDIM) ? f2bf(wsrc[(size_t)jlog * EDIM + k]) : (u16)0;
  }
  int t2 = tid - 2 * 1024 * EPAD;
  if (t2 >= 0 && t2 < 2 * 1024) {
    int d = t2 >> 10; int p = t2 & 1023;
    int w = p >> 7, q = (p >> 4) & 7, ul = p & 15;
    int jlog = (q & 3) * 256 + w * 32 + (q >> 2) * 16 + ul;
    bias[t2] = d ? (bih_b[jlog] + bhh_b[jlog]) : (bih_f[jlog] + bhh_f[jlog]);
  }
}

// ---------------- emb -> bf16, K padded 300->320 (one-time) ----------------
__global__ void embconv_kernel(const float* emb, u16* embbf)
{
  int r = blockIdx.x;
  int k = threadIdx.x;     // 320
  embbf[(size_t)r * EPAD + k] = (k < EDIM) ? f2bf(emb[(size_t)r * EDIM + k]) : (u16)0;
}

// ---------------- Whh -> i8 quant + MFMA-fragment pack (8-wave pack order) ----------------
__global__ void whhq_kernel(const float* whh_f, const float* whh_b, char* wpk, float* sw)
{
  int jp = blockIdx.x;             // 0..2047 = d*1024 + pack p
  int t = threadIdx.x;             // 64
  int d = jp >> 10, p = jp & 1023;
  int w = p >> 7, q = (p >> 4) & 7, ul = p & 15;
  int jlog = (q & 3) * 256 + w * 32 + (q >> 2) * 16 + ul;
  const float* src = (d ? whh_b : whh_f) + (size_t)jlog * 256;
  float v[4]; float m = 0.f;
  #pragma unroll
  for (int kk = 0; kk < 4; ++kk) { v[kk] = src[t * 4 + kk]; m = fmaxf(m, fabsf(v[kk])); }
  #pragma unroll
  for (int off = 32; off > 0; off >>= 1) m = fmaxf(m, __shfl_xor(m, off));
  float sunit = m / 127.f;
  if (sunit < 1e-30f) sunit = 1e-30f;
  unsigned int pk = 0;
  #pragma unroll
  for (int kk = 0; kk < 4; ++kk) {
    int qv = (int)rintf(v[kk] / sunit);
    qv = qv > 127 ? 127 : (qv < -127 ? -127 : qv);
    pk |= ((unsigned int)(qv & 255)) << (8 * kk);
  }
  // frag entry (d,w,q,kc,lane=kg*16+ul): bytes = Wq[jlog][kc*64+kg*16 .. +16)
  size_t base = ((((size_t)(d * 8 + w) * 8 + q) * 4 + (t >> 4)) * 64
                 + (((t >> 2) & 3) * 16 + ul)) * 16 + (t & 3) * 4;
  *(unsigned int*)&wpk[base] = pk;
  if (t == 0) sw[jp] = sunit / 127.f;
}

// ---------------- fused gather + input projection GEMM, full-N per block ----------------
// Block = 128 M-rows x full N=1024. A (token gather) staged ONCE full-K in 80KB LDS;
// B double-buffered 2x16KB from L2. Epilogue: direct sigma-permuted u16x4 stores.
__global__ void __launch_bounds__(256, 1)
gemm_chunk_kernel(const int* __restrict__ x1, const int* __restrict__ x2,
                  const u16* __restrict__ embbf, const u16* __restrict__ wih_bf,
                  const float* __restrict__ bias, u16* __restrict__ ginc,
                  int t0, int T, int logT)
{
  __shared__ __align__(16) u16 As[5 * 8192];    // 80KB: [kt][16 grp][1024B]
  __shared__ __align__(16) u16 Bs[2 * 8192];    // 32KB double buffer

  int m0 = blockIdx.x * 128;
  int d  = m0 >> (8 + logT);
  int tl = (m0 >> 8) & (T - 1);
  int R0 = m0 & 255;                 // 0 or 128
  int lane = threadIdx.x & 63;
  int w = threadIdx.x >> 6;          // 4 waves
  int wm = w >> 1, wn = w & 1;

  const int* x = (R0 >> 7) ? x2 : x1;
  int t = t0 + tl;
  int tpos = d ? (255 - t) : t;

  int ar  = lane >> 3;               // row within 8-row stripe
  int acb = (lane & 7) * 16;         // byte col (16B slot)
  int swz = ar << 4;

  int toks[4];
  #pragma unroll
  for (int i = 0; i < 4; ++i) {
    int lrow = (i * 4 + w) * 8 + ar;
    toks[i] = x[((R0 + lrow) & 127) * 256 + tpos];
  }

  const char* Bbase = (const char*)(wih_bf + (size_t)d * 1024 * EPAD);
  const char* Ebase = (const char*)embbf;

  // stage full-K A (once) + B(nt=0, kt=0) into buf 0
  #pragma unroll
  for (int kt = 0; kt < 5; ++kt)
    #pragma unroll
    for (int i = 0; i < 4; ++i)
      gload_lds16(Ebase + (size_t)toks[i] * 640 + kt * 128 + (acb ^ swz),
                  (char*)As + kt * 16384 + (i * 4 + w) * 1024);
  #pragma unroll
  for (int i = 0; i < 4; ++i) {
    int lrow = (i * 4 + w) * 8 + ar;
    gload_lds16(Bbase + (size_t)lrow * 640 + (acb ^ swz),
                (char*)Bs + (i * 4 + w) * 1024);
  }
  __syncthreads();

  size_t rowbase = (size_t)(d * T + tl) * 256 + R0;
  int buf = 0;

  for (int nt = 0; nt < 8; ++nt) {
    f32x4v acc[4][4] = {};
    for (int kt = 0; kt < 5; ++kt) {
      // prefetch next B tile into buf^1
      int nkt = kt + 1, nnt = nt;
      if (nkt == 5) { nkt = 0; nnt = nt + 1; }
      if (nnt < 8) {
        #pragma unroll
        for (int i = 0; i < 4; ++i) {
          int lrow = nnt * 128 + (i * 4 + w) * 8 + ar;
          gload_lds16(Bbase + (size_t)lrow * 640 + nkt * 128 + (acb ^ swz),
                      (char*)Bs + (buf ^ 1) * 16384 + (i * 4 + w) * 1024);
        }
      }
      // compute As[kt] x Bs[buf]
      #pragma unroll
      for (int kc = 0; kc < 2; ++kc) {
        s16x8 a[4], b[4];
        int cb = kc * 64 + (lane >> 4) * 16;
        #pragma unroll
        for (int mf = 0; mf < 4; ++mf) {
          int rr = wm * 64 + mf * 16 + (lane & 15);
          a[mf] = *(const s16x8*)((const char*)As + kt * 16384 + rr * 128 + (cb ^ ((rr & 7) << 4)));
        }
        #pragma unroll
        for (int nf = 0; nf < 4; ++nf) {
          int rr = wn * 64 + nf * 16 + (lane & 15);
          b[nf] = *(const s16x8*)((const char*)Bs + buf * 16384 + rr * 128 + (cb ^ ((rr & 7) << 4)));
        }
        #pragma unroll
        for (int mf = 0; mf < 4; ++mf)
          #pragma unroll
          for (int nf = 0; nf < 4; ++nf)
            acc[mf][nf] = __builtin_amdgcn_mfma_f32_16x16x32_bf16(a[mf], b[nf], acc[mf][nf], 0, 0, 0);
      }
      __syncthreads();
      buf ^= 1;
    }

    // epilogue nt: bias, direct sigma store (u16x4 = 4 gates of one cell)
    float bv[4];
    #pragma unroll
    for (int nf = 0; nf < 4; ++nf)
      bv[nf] = bias[d * 1024 + nt * 128 + wn * 64 + nf * 16 + (lane & 15)];
    int scol = nt * 128 + wn * 64 + (lane & 15) * 4;
    #pragma unroll
    for (int mf = 0; mf < 4; ++mf)
      #pragma unroll
      for (int i = 0; i < 4; ++i) {
        int row = wm * 64 + mf * 16 + (lane >> 4) * 4 + i;
        u16x4 v;
        #pragma unroll
        for (int nf = 0; nf < 4; ++nf)
          v[nf] = f2bf(acc[mf][nf][i] + bv[nf]);
        *(u16x4*)(ginc + (rowbase + row) * 1024 + scol) = v;
      }
  }
}

// ---------------- recurrent bi-LSTM (R7 structure, native __expf, unclamped prefetch) ----------------
// 256 blocks = 2 dir x 128 two-row tiles; 8 waves; wave w owns u in [w*32,(w+1)*32) x 4 gates.
// ONE lgkm-only barrier per step; h double-buffered in LDS.
__global__ void __launch_bounds__(512)
lstm_chunk_kernel(const u16* __restrict__ ginc, const i32x4* __restrict__ wpk,
                  const float* __restrict__ sw, char* hsave,
                  float* cstate, float* vaccst, float* vout,
                  const int* len1, const int* len2, int t0, int T)
{
  __shared__ __align__(16) char h_lds[2][2][288];   // [parity][row][256 k +pad]

  const int bid = blockIdx.x;
  const int d = bid >> 7, bt = bid & 127;
  const int tid = threadIdx.x;
  const int lane = tid & 63, w = tid >> 6;          // 8 waves
  const int cl = lane & 15;

  // Whh i8 fragments -> registers; per-column scales (pack order)
  i32x4 bfr[8][4];
  #pragma unroll
  for (int q = 0; q < 8; ++q)
    #pragma unroll
    for (int kc = 0; kc < 4; ++kc)
      bfr[q][kc] = wpk[(((size_t)(d * 8 + w) * 8 + q) * 4 + kc) * 64 + lane];
  float swl[8];
  #pragma unroll
  for (int q = 0; q < 8; ++q)
    swl[q] = sw[d * 1024 + w * 128 + q * 16 + cl];

  const int R0 = bt * 2;
  {
    int r = tid >> 8, u = tid & 255;
    h_lds[0][r][u] = (t0 > 0) ? hsave[((size_t)d * 256 + R0 + r) * 256 + u] : (char)0;
  }

  int lm0 = ((R0 >> 7) ? len2 : len1)[R0 & 127] - 1;
  int lm1 = (((R0 + 1) >> 7) ? len2 : len1)[(R0 + 1) & 127] - 1;

  const bool gl = (lane < 16);
  float c[2][2] = {{0.f,0.f},{0.f,0.f}}, va[2][2] = {{0.f,0.f},{0.f,0.f}};
  if (t0 > 0 && gl) {
    #pragma unroll
    for (int r = 0; r < 2; ++r)
      #pragma unroll
      for (int uh = 0; uh < 2; ++uh) {
        size_t sidx = ((size_t)d * 256 + R0 + r) * 256 + (w * 32 + uh * 16 + cl);
        c[r][uh] = cstate[sidx];
        va[r][uh] = vaccst[sidx];
      }
  }

  const size_t GSTEP = (size_t)256 * 1024;
  const u16* gbase = ginc + ((size_t)d * T * 256 + R0) * 1024;
  u16x4 gv[2][2];
  if (gl) {
    #pragma unroll
    for (int r = 0; r < 2; ++r)
      #pragma unroll
      for (int uh = 0; uh < 2; ++uh)
        gv[r][uh] = *(const u16x4*)(gbase + (size_t)r * 1024 + w * 128 + uh * 64 + cl * 4);
  }
  __syncthreads();

  const bool final_chunk = (t0 + T == 256);
  int par = 0;

  for (int tl = 0; tl < T; ++tl) {
    // prefetch next step's gates — unclamped (1 pad slab allocated), flies across barrier
    const u16* gnb = gbase + GSTEP * (size_t)(tl + 1);
    u16x4 gvn[2][2];
    if (gl) {
      #pragma unroll
      for (int r = 0; r < 2; ++r)
        #pragma unroll
        for (int uh = 0; uh < 2; ++uh)
          gvn[r][uh] = *(const u16x4*)(gnb + (size_t)r * 1024 + w * 128 + uh * 64 + cl * 4);
    }

    // A-frags (rows 0,1 real; others zero)
    i32x4 a[4] = {{0,0,0,0},{0,0,0,0},{0,0,0,0},{0,0,0,0}};
    if (cl < 2) {
      #pragma unroll
      for (int kc = 0; kc < 4; ++kc)
        a[kc] = *(const i32x4*)&h_lds[par][cl][kc * 64 + (lane >> 4) * 16];
    }
    i32x4 acc[8];
    #pragma unroll
    for (int q = 0; q < 8; ++q) {
      i32x4 z = {0, 0, 0, 0};
      #pragma unroll
      for (int kc = 0; kc < 4; ++kc)
        z = __builtin_amdgcn_mfma_i32_16x16x64_i8(a[kc], bfr[q][kc], z, 0, 0, 0);
      acc[q] = z;
    }

    // in-register gate math on lanes 0..15 (cells: 2 rows x 2 uh) — native exp
    if (gl) {
      int tmap = d ? (255 - (t0 + tl)) : (t0 + tl);
      #pragma unroll
      for (int r = 0; r < 2; ++r) {
        int lm = r ? lm1 : lm0;
        #pragma unroll
        for (int uh = 0; uh < 2; ++uh) {
          float s0 = (float)acc[uh * 4 + 0][r] * swl[uh * 4 + 0] + bf2f(gv[r][uh][0]);
          float s1 = (float)acc[uh * 4 + 1][r] * swl[uh * 4 + 1] + bf2f(gv[r][uh][1]);
          float s2 = (float)acc[uh * 4 + 2][r] * swl[uh * 4 + 2] + bf2f(gv[r][uh][2]);
          float s3 = (float)acc[uh * 4 + 3][r] * swl[uh * 4 + 3] + bf2f(gv[r][uh][3]);
          float I = __builtin_amdgcn_rcpf(1.f + __expf(-s0));
          float F = __builtin_amdgcn_rcpf(1.f + __expf(-s1));
          float G = 1.f - 2.f * __builtin_amdgcn_rcpf(__expf(2.f * s2) + 1.f);
          float O = __builtin_amdgcn_rcpf(1.f + __expf(-s3));
          float cn = F * c[r][uh] + I * G;
          c[r][uh] = cn;
          float hn = O * (1.f - 2.f * __builtin_amdgcn_rcpf(__expf(2.f * cn) + 1.f));
          if (tmap < lm) va[r][uh] += hn;
          h_lds[par ^ 1][r][w * 32 + uh * 16 + cl] = (char)(int)rintf(hn * 127.f);
        }
      }
    }
    lds_barrier();
    #pragma unroll
    for (int r = 0; r < 2; ++r)
      #pragma unroll
      for (int uh = 0; uh < 2; ++uh)
        gv[r][uh] = gvn[r][uh];
    par ^= 1;
  }

  if (gl) {
    #pragma unroll
    for (int r = 0; r < 2; ++r) {
      int lm = r ? lm1 : lm0;
      #pragma unroll
      for (int uh = 0; uh < 2; ++uh) {
        int u = w * 32 + uh * 16 + cl;
        size_t sidx = ((size_t)d * 256 + R0 + r) * 256 + u;
        cstate[sidx] = c[r][uh];
        vaccst[sidx] = va[r][uh];
        if (final_chunk) {
          int RR = R0 + r;
          vout[((size_t)(RR >> 7) * 128 + (RR & 127)) * 512 + d * 256 + u] = va[r][uh] / (float)lm;
        }
      }
    }
  }
  if (!final_chunk) {
    int r = tid >> 8, u = tid & 255;
    hsave[((size_t)d * 256 + R0 + r) * 256 + u] = h_lds[par][r][u];
  }
}

// ---------------- MLP head ----------------
__global__ void mlp_kernel(const float* v, const float* W1, const float* b1,
                           const float* W2, const float* b2, const float* Wo, const float* bo,
                           float* out)
{
  __shared__ float vec[512];
  __shared__ float a1[512];
  __shared__ float red[4];
  int b = blockIdx.x;
  int tid = threadIdx.x;   // 256
  for (int i = tid; i < 512; i += 256)
    vec[i] = fabsf(v[(size_t)b * 512 + i] - v[(size_t)(128 + b) * 512 + i]);
  __syncthreads();
  for (int j = tid; j < 512; j += 256) {
    float s = b1[j];
    const float* wr = W1 + (size_t)j * 512;
    for (int k = 0; k < 512; ++k) s += vec[k] * wr[k];
    a1[j] = fmaxf(s, 0.f);
  }
  __syncthreads();
  float s = b2[tid];
  {
    const float* wr = W2 + (size_t)tid * 512;
    for (int k = 0; k < 512; ++k) s += a1[k] * wr[k];
  }
  float p = fmaxf(s, 0.f) * Wo[tid];
  for (int off = 32; off > 0; off >>= 1) p += __shfl_down(p, off);
  if ((tid & 63) == 0) red[tid >> 6] = p;
  __syncthreads();
  if (tid == 0) {
    float logit = red[0] + red[1] + red[2] + red[3] + bo[0];
    out[b] = logit;
    out[128 + b] = 1.f / (1.f + __expf(-logit));
  }
}

extern "C" void kernel_launch(void* const* d_in, const int* in_sizes, int n_in,
                              void* d_out, int out_size, void* d_ws, size_t ws_size,
                              hipStream_t stream)
{
  const int*   x1    = (const int*)d_in[0];
  const int*   x2    = (const int*)d_in[1];
  const int*   len1  = (const int*)d_in[2];
  const int*   len2  = (const int*)d_in[3];
  const float* emb   = (const float*)d_in[4];
  const float* wih_f = (const float*)d_in[5];
  const float* whh_f = (const float*)d_in[6];
  const float* bih_f = (const float*)d_in[7];
  const float* bhh_f = (const float*)d_in[8];
  const float* wih_b = (const float*)d_in[9];
  const float* whh_b = (const float*)d_in[10];
  const float* bih_b = (const float*)d_in[11];
  const float* bhh_b = (const float*)d_in[12];
  const float* W1    = (const float*)d_in[13];
  const float* b1    = (const float*)d_in[14];
  const float* W2    = (const float*)d_in[15];
  const float* b2    = (const float*)d_in[16];
  const float* Wo    = (const float*)d_in[17];
  const float* bo    = (const float*)d_in[18];

  char* p = (char*)d_ws;
  u16*   wih_bf = (u16*)p;          p += SZ_WIH;
  char*  wpk    = (char*)p;         p += SZ_WPK;
  float* swp    = (float*)p;        p += SZ_SW;
  float* bias   = (float*)p;        p += SZ_BIAS;
  char*  hsave  = (char*)p;         p += SZ_HSV;
  float* cst    = (float*)p;        p += SZ_CST;
  float* vac    = (float*)p;        p += SZ_VAC;
  float* vout   = (float*)p;        p += SZ_VOUT;
  u16*   embbf  = (u16*)p;          p += SZ_EMB;

  int T = 256;
  while (T > 1 && FIXED_B + (size_t)T * PER_T > ws_size) T >>= 1;
  int logT = __builtin_ctz((unsigned)T);
  u16* ginc = (u16*)p;              // [(d*T+tl)*256 + R][1024 sigma-cols] u16 (+1 pad slab)

  {
    int total = 2 * 1024 * EPAD + 2 * 1024;
    prep_kernel<<<(total + 255) / 256, 256, 0, stream>>>(
        wih_f, bih_f, bhh_f, wih_b, bih_b, bhh_b, wih_bf, bias);
  }
  whhq_kernel<<<2048, 64, 0, stream>>>(whh_f, whh_b, wpk, swp);
  embconv_kernel<<<VOCAB, EPAD, 0, stream>>>(emb, embbf);

  int nch = 256 / T;
  for (int ch = 0; ch < nch; ++ch) {
    int tt0 = ch * T;
    gemm_chunk_kernel<<<dim3(4 * T), 256, 0, stream>>>(x1, x2, embbf, wih_bf, bias,
                                                       ginc, tt0, T, logT);
    lstm_chunk_kernel<<<256, 512, 0, stream>>>(ginc, (const i32x4*)wpk, swp, hsave,
                                               cst, vac, vout, len1, len2, tt0, T);
  }

  mlp_kernel<<<128, 256, 0, stream>>>(vout, W1, b1, W2, b2, Wo, bo, (float*)d_out);
}

// Round 14
// 500.521 us; speedup vs baseline: 1.4593x; 1.1712x over previous
//
#include <hip/hip_runtime.h>
#include <hip/hip_bf16.h>
#include <math.h>

typedef unsigned short u16;
typedef short s16x8 __attribute__((ext_vector_type(8)));
typedef float f32x4v __attribute__((ext_vector_type(4)));
typedef int i32x4 __attribute__((ext_vector_type(4)));
typedef unsigned short u16x4 __attribute__((ext_vector_type(4)));

#define EDIM 300
#define EPAD 320
#define VOCAB 50000

// ---- fixed workspace layout (bytes) ----
static constexpr size_t SZ_WIH  = (size_t)2 * 1024 * EPAD * 2;   // bf16 [2][1024 pack][320]
static constexpr size_t SZ_WPK  = (size_t)2 * 1024 * 256;        // i8 packed Whh frags
static constexpr size_t SZ_SW   = (size_t)2 * 1024 * 4;          // f32 per-row scale (pack order)
static constexpr size_t SZ_BIAS = (size_t)2 * 1024 * 4;          // f32 (pack order)
static constexpr size_t SZ_HSV  = (size_t)2 * 256 * 256;         // i8 h chunk-boundary save
static constexpr size_t SZ_CST  = (size_t)2 * 256 * 256 * 4;     // f32 c-state
static constexpr size_t SZ_VAC  = (size_t)2 * 256 * 256 * 4;     // f32 vacc-state
static constexpr size_t SZ_VOUT = (size_t)2 * 128 * 512 * 4;     // f32 [2][128][512]
static constexpr size_t SZ_EMB  = (size_t)VOCAB * EPAD * 2;      // bf16 emb table padded (32 MB)
static constexpr size_t SZ_PAD  = (size_t)512 * 1024;            // +1 slab: unclamped prefetch
static constexpr size_t FIXED_B = SZ_WIH + SZ_WPK + SZ_SW + SZ_BIAS + SZ_HSV + SZ_CST + SZ_VAC + SZ_VOUT + SZ_EMB + SZ_PAD;
static constexpr size_t PER_T   = (size_t)512 * 1024 * 2;        // ginc per step (1 MB, both dirs)

// pack permutation: pack p = w*128 + q*16 + ul  (w=wave 0..7, q=uh*4+gate, ul 0..15)
//   -> logical Whh/Wih row jlog = (q&3)*256 + w*32 + (q>>2)*16 + ul
// sigma (ginc column) s = w*128 + uh*64 + ul*4 + gate  (gates contiguous per cell)

__device__ __forceinline__ float bf2f(u16 u) {
  union { float f; unsigned int i; } v; v.i = ((unsigned int)u) << 16; return v.f;
}
__device__ __forceinline__ u16 f2bf(float f) {
  union { float f; unsigned int i; } v; v.f = f;
  unsigned int r = v.i + 0x7fffu + ((v.i >> 16) & 1u);   // RNE (finite inputs)
  return (u16)(r >> 16);
}
__device__ __forceinline__ void gload_lds16(const void* g, void* l) {
  __builtin_amdgcn_global_load_lds((const __attribute__((address_space(1))) void*)g,
                                   (__attribute__((address_space(3))) void*)l, 16, 0, 0);
}
// order LDS ops across waves WITHOUT draining vmcnt
__device__ __forceinline__ void lds_barrier() {
  asm volatile("s_waitcnt lgkmcnt(0)" ::: "memory");
  __builtin_amdgcn_s_barrier();
}
// intra-wave LDS exchange fence: compiler may otherwise hoist the ds_read past
// the exec-masked ds_writes (per-thread alias analysis sees disjoint offsets).
// HW processes a wave's DS ops in order; this pins the compiler + waits retire.
__device__ __forceinline__ void wave_lds_fence() {
  asm volatile("s_waitcnt lgkmcnt(0)" ::: "memory");
  __builtin_amdgcn_sched_barrier(0);
}

// ---------------- prep: Wih->bf16 padded (pack-row order), bias sum (pack order) ----------------
__global__ void prep_kernel(const float* wih_f, const float* bih_f, const float* bhh_f,
                            const float* wih_b, const float* bih_b, const float* bhh_b,
                            u16* wih_bf, float* bias)
{
  int tid = blockIdx.x * blockDim.x + threadIdx.x;
  if (tid < 2 * 1024 * EPAD) {
    int d = tid / (1024 * EPAD); int rr = tid % (1024 * EPAD);
    int p = rr / EPAD; int k = rr % EPAD;
    int w = p >> 7, q = (p >> 4) & 7, ul = p & 15;
    int jlog = (q & 3) * 256 + w * 32 + (q >> 2) * 16 + ul;
    const float* wsrc = d ? wih_b : wih_f;
    wih_bf[tid] = (k < EDIM) ? f2bf(wsrc[(size_t)jlog * EDIM + k]) : (u16)0;
  }
  int t2 = tid - 2 * 1024 * EPAD;
  if (t2 >= 0 && t2 < 2 * 1024) {
    int d = t2 >> 10; int p = t2 & 1023;
    int w = p >> 7, q = (p >> 4) & 7, ul = p & 15;
    int jlog = (q & 3) * 256 + w * 32 + (q >> 2) * 16 + ul;
    bias[t2] = d ? (bih_b[jlog] + bhh_b[jlog]) : (bih_f[jlog] + bhh_f[jlog]);
  }
}

// ---------------- emb -> bf16, K padded 300->320 (one-time) ----------------
__global__ void embconv_kernel(const float* emb, u16* embbf)
{
  int r = blockIdx.x;
  int k = threadIdx.x;     // 320
  embbf[(size_t)r * EPAD + k] = (k < EDIM) ? f2bf(emb[(size_t)r * EDIM + k]) : (u16)0;
}

// ---------------- Whh -> i8 quant + MFMA-fragment pack (8-wave pack order) ----------------
__global__ void whhq_kernel(const float* whh_f, const float* whh_b, char* wpk, float* sw)
{
  int jp = blockIdx.x;             // 0..2047 = d*1024 + pack p
  int t = threadIdx.x;             // 64
  int d = jp >> 10, p = jp & 1023;
  int w = p >> 7, q = (p >> 4) & 7, ul = p & 15;
  int jlog = (q & 3) * 256 + w * 32 + (q >> 2) * 16 + ul;
  const float* src = (d ? whh_b : whh_f) + (size_t)jlog * 256;
  float v[4]; float m = 0.f;
  #pragma unroll
  for (int kk = 0; kk < 4; ++kk) { v[kk] = src[t * 4 + kk]; m = fmaxf(m, fabsf(v[kk])); }
  #pragma unroll
  for (int off = 32; off > 0; off >>= 1) m = fmaxf(m, __shfl_xor(m, off));
  float sunit = m / 127.f;
  if (sunit < 1e-30f) sunit = 1e-30f;
  unsigned int pk = 0;
  #pragma unroll
  for (int kk = 0; kk < 4; ++kk) {
    int qv = (int)rintf(v[kk] / sunit);
    qv = qv > 127 ? 127 : (qv < -127 ? -127 : qv);
    pk |= ((unsigned int)(qv & 255)) << (8 * kk);
  }
  // frag entry (d,w,q,kc,lane=kg*16+ul): bytes = Wq[jlog][kc*64+kg*16 .. +16)
  size_t base = ((((size_t)(d * 8 + w) * 8 + q) * 4 + (t >> 4)) * 64
                 + (((t >> 2) & 3) * 16 + ul)) * 16 + (t & 3) * 4;
  *(unsigned int*)&wpk[base] = pk;
  if (t == 0) sw[jp] = sunit / 127.f;
}

// ---------------- fused gather + input projection GEMM, full-N per block ----------------
// Block = 128 M-rows x full N=1024. A (token gather) staged ONCE full-K in 80KB LDS;
// B double-buffered 2x16KB from L2. Epilogue: direct sigma-permuted u16x4 stores.
__global__ void __launch_bounds__(256, 1)
gemm_chunk_kernel(const int* __restrict__ x1, const int* __restrict__ x2,
                  const u16* __restrict__ embbf, const u16* __restrict__ wih_bf,
                  const float* __restrict__ bias, u16* __restrict__ ginc,
                  int t0, int T, int logT)
{
  __shared__ __align__(16) u16 As[5 * 8192];    // 80KB: [kt][16 grp][1024B]
  __shared__ __align__(16) u16 Bs[2 * 8192];    // 32KB double buffer

  int m0 = blockIdx.x * 128;
  int d  = m0 >> (8 + logT);
  int tl = (m0 >> 8) & (T - 1);
  int R0 = m0 & 255;                 // 0 or 128
  int lane = threadIdx.x & 63;
  int w = threadIdx.x >> 6;          // 4 waves
  int wm = w >> 1, wn = w & 1;

  const int* x = (R0 >> 7) ? x2 : x1;
  int t = t0 + tl;
  int tpos = d ? (255 - t) : t;

  int ar  = lane >> 3;               // row within 8-row stripe
  int acb = (lane & 7) * 16;         // byte col (16B slot)
  int swz = ar << 4;

  int toks[4];
  #pragma unroll
  for (int i = 0; i < 4; ++i) {
    int lrow = (i * 4 + w) * 8 + ar;
    toks[i] = x[((R0 + lrow) & 127) * 256 + tpos];
  }

  const char* Bbase = (const char*)(wih_bf + (size_t)d * 1024 * EPAD);
  const char* Ebase = (const char*)embbf;

  // stage full-K A (once) + B(nt=0, kt=0) into buf 0
  #pragma unroll
  for (int kt = 0; kt < 5; ++kt)
    #pragma unroll
    for (int i = 0; i < 4; ++i)
      gload_lds16(Ebase + (size_t)toks[i] * 640 + kt * 128 + (acb ^ swz),
                  (char*)As + kt * 16384 + (i * 4 + w) * 1024);
  #pragma unroll
  for (int i = 0; i < 4; ++i) {
    int lrow = (i * 4 + w) * 8 + ar;
    gload_lds16(Bbase + (size_t)lrow * 640 + (acb ^ swz),
                (char*)Bs + (i * 4 + w) * 1024);
  }
  __syncthreads();

  size_t rowbase = (size_t)(d * T + tl) * 256 + R0;
  int buf = 0;

  for (int nt = 0; nt < 8; ++nt) {
    f32x4v acc[4][4] = {};
    for (int kt = 0; kt < 5; ++kt) {
      // prefetch next B tile into buf^1
      int nkt = kt + 1, nnt = nt;
      if (nkt == 5) { nkt = 0; nnt = nt + 1; }
      if (nnt < 8) {
        #pragma unroll
        for (int i = 0; i < 4; ++i) {
          int lrow = nnt * 128 + (i * 4 + w) * 8 + ar;
          gload_lds16(Bbase + (size_t)lrow * 640 + nkt * 128 + (acb ^ swz),
                      (char*)Bs + (buf ^ 1) * 16384 + (i * 4 + w) * 1024);
        }
      }
      // compute As[kt] x Bs[buf]
      #pragma unroll
      for (int kc = 0; kc < 2; ++kc) {
        s16x8 a[4], b[4];
        int cb = kc * 64 + (lane >> 4) * 16;
        #pragma unroll
        for (int mf = 0; mf < 4; ++mf) {
          int rr = wm * 64 + mf * 16 + (lane & 15);
          a[mf] = *(const s16x8*)((const char*)As + kt * 16384 + rr * 128 + (cb ^ ((rr & 7) << 4)));
        }
        #pragma unroll
        for (int nf = 0; nf < 4; ++nf) {
          int rr = wn * 64 + nf * 16 + (lane & 15);
          b[nf] = *(const s16x8*)((const char*)Bs + buf * 16384 + rr * 128 + (cb ^ ((rr & 7) << 4)));
        }
        #pragma unroll
        for (int mf = 0; mf < 4; ++mf)
          #pragma unroll
          for (int nf = 0; nf < 4; ++nf)
            acc[mf][nf] = __builtin_amdgcn_mfma_f32_16x16x32_bf16(a[mf], b[nf], acc[mf][nf], 0, 0, 0);
      }
      __syncthreads();
      buf ^= 1;
    }

    // epilogue nt: bias, direct sigma store (u16x4 = 4 gates of one cell)
    float bv[4];
    #pragma unroll
    for (int nf = 0; nf < 4; ++nf)
      bv[nf] = bias[d * 1024 + nt * 128 + wn * 64 + nf * 16 + (lane & 15)];
    int scol = nt * 128 + wn * 64 + (lane & 15) * 4;
    #pragma unroll
    for (int mf = 0; mf < 4; ++mf)
      #pragma unroll
      for (int i = 0; i < 4; ++i) {
        int row = wm * 64 + mf * 16 + (lane >> 4) * 4 + i;
        u16x4 v;
        #pragma unroll
        for (int nf = 0; nf < 4; ++nf)
          v[nf] = f2bf(acc[mf][nf][i] + bv[nf]);
        *(u16x4*)(ginc + (rowbase + row) * 1024 + scol) = v;
      }
  }
}

// ---------------- recurrent bi-LSTM: R7 tiling + ALL-LANE gate math (fenced exchange) ----------------
// 256 blocks = 2 dir x 128 two-row tiles; 8 waves; wave w owns u in [w*32,(w+1)*32) x 4 gates.
// After MFMA, lanes<16 stage raw i32 preacts to a per-wave LDS slab [64 cells][4 gates];
// wave_lds_fence() pins write->read order; every lane reads ONE cell (cell idx == lane).
// ONE lgkm-only block barrier per step.
__global__ void __launch_bounds__(512)
lstm_chunk_kernel(const u16* __restrict__ ginc, const i32x4* __restrict__ wpk,
                  const float* __restrict__ sw, char* hsave,
                  float* cstate, float* vaccst, float* vout,
                  const int* len1, const int* len2, int t0, int T)
{
  __shared__ __align__(16) char h_lds[2][2][288];   // [parity][row][256 k +pad]
  __shared__ __align__(16) int gstage[8][64][4];    // [wave][cell][gate] raw i32 preacts

  const int bid = blockIdx.x;
  const int d = bid >> 7, bt = bid & 127;
  const int tid = threadIdx.x;
  const int lane = tid & 63, w = tid >> 6;          // 8 waves
  const int cl = lane & 15;

  // owned cell (all 64 lanes): lane = cr*32 + cuh*16 + cl
  const int cr  = lane >> 5;
  const int cuh = (lane >> 4) & 1;
  const int cu  = w * 32 + cuh * 16 + cl;           // u index of owned cell

  // Whh i8 fragments -> registers; per-owned-cell scales (pack order)
  i32x4 bfr[8][4];
  #pragma unroll
  for (int q = 0; q < 8; ++q)
    #pragma unroll
    for (int kc = 0; kc < 4; ++kc)
      bfr[q][kc] = wpk[(((size_t)(d * 8 + w) * 8 + q) * 4 + kc) * 64 + lane];
  float swl4[4];
  #pragma unroll
  for (int g = 0; g < 4; ++g)
    swl4[g] = sw[d * 1024 + w * 128 + (cuh * 4 + g) * 16 + cl];

  const int R0 = bt * 2;
  {
    int r = tid >> 8, u = tid & 255;
    h_lds[0][r][u] = (t0 > 0) ? hsave[((size_t)d * 256 + R0 + r) * 256 + u] : (char)0;
  }

  const int RR = R0 + cr;
  const int lm = ((RR >> 7) ? len2 : len1)[RR & 127] - 1;
  const size_t sidx = ((size_t)d * 256 + RR) * 256 + cu;
  float c = 0.f, va = 0.f;
  if (t0 > 0) { c = cstate[sidx]; va = vaccst[sidx]; }

  const size_t GSTEP = (size_t)256 * 1024;
  const u16* gcell = ginc + ((size_t)d * T * 256 + RR) * 1024 + w * 128 + cuh * 64 + cl * 4;
  u16x4 gv = *(const u16x4*)gcell;
  __syncthreads();

  const bool final_chunk = (t0 + T == 256);
  int par = 0;

  for (int tl = 0; tl < T; ++tl) {
    // prefetch next step's gates — unclamped (pad slab), flies across the barrier
    u16x4 gvn = *(const u16x4*)(gcell + GSTEP * (size_t)(tl + 1));

    // A-frags (rows 0,1 real; others zero) — mask is (cl<2) only:
    // rows live in lanes {0,1,16,17,32,33,48,49}; lane>>4 selects the k-segment.
    i32x4 a[4] = {{0,0,0,0},{0,0,0,0},{0,0,0,0},{0,0,0,0}};
    if (cl < 2) {
      #pragma unroll
      for (int kc = 0; kc < 4; ++kc)
        a[kc] = *(const i32x4*)&h_lds[par][cl][kc * 64 + (lane >> 4) * 16];
    }
    i32x4 acc[8];
    #pragma unroll
    for (int q = 0; q < 8; ++q) {
      i32x4 z = {0, 0, 0, 0};
      #pragma unroll
      for (int kc = 0; kc < 4; ++kc)
        z = __builtin_amdgcn_mfma_i32_16x16x64_i8(a[kc], bfr[q][kc], z, 0, 0, 0);
      acc[q] = z;
    }

    // stage raw preacts: lanes<16 hold cells (r2 = reg, uh2, ul=lane) of C/D rows 0,1
    if (lane < 16) {
      #pragma unroll
      for (int r2 = 0; r2 < 2; ++r2)
        #pragma unroll
        for (int uh2 = 0; uh2 < 2; ++uh2) {
          i32x4 v = { acc[uh2 * 4 + 0][r2], acc[uh2 * 4 + 1][r2],
                      acc[uh2 * 4 + 2][r2], acc[uh2 * 4 + 3][r2] };
          *(i32x4*)&gstage[w][r2 * 32 + uh2 * 16 + lane][0] = v;
        }
    }
    // FENCE: without this the compiler may reorder the cross-lane read before
    // the exec-masked writes (per-thread AA sees disjoint offsets) — R13's bug.
    wave_lds_fence();
    i32x4 g4 = *(const i32x4*)&gstage[w][lane][0];

    // gate math — ALL 64 lanes, 1 cell each
    {
      float s0 = (float)g4[0] * swl4[0] + bf2f(gv[0]);
      float s1 = (float)g4[1] * swl4[1] + bf2f(gv[1]);
      float s2 = (float)g4[2] * swl4[2] + bf2f(gv[2]);
      float s3 = (float)g4[3] * swl4[3] + bf2f(gv[3]);
      float I = __builtin_amdgcn_rcpf(1.f + __expf(-s0));
      float F = __builtin_amdgcn_rcpf(1.f + __expf(-s1));
      float G = 1.f - 2.f * __builtin_amdgcn_rcpf(__expf(2.f * s2) + 1.f);
      float O = __builtin_amdgcn_rcpf(1.f + __expf(-s3));
      float cn = F * c + I * G;
      c = cn;
      float hn = O * (1.f - 2.f * __builtin_amdgcn_rcpf(__expf(2.f * cn) + 1.f));
      int tmap = d ? (255 - (t0 + tl)) : (t0 + tl);
      if (tmap < lm) va += hn;
      h_lds[par ^ 1][cr][cu] = (char)(int)rintf(hn * 127.f);
    }
    lds_barrier();
    gv = gvn;
    par ^= 1;
  }

  cstate[sidx] = c;
  vaccst[sidx] = va;
  if (final_chunk) {
    vout[((size_t)(RR >> 7) * 128 + (RR & 127)) * 512 + d * 256 + cu] = va / (float)lm;
  } else {
    int r = tid >> 8, u = tid & 255;
    hsave[((size_t)d * 256 + R0 + r) * 256 + u] = h_lds[par][r][u];
  }
}

// ---------------- MLP head ----------------
__global__ void mlp_kernel(const float* v, const float* W1, const float* b1,
                           const float* W2, const float* b2, const float* Wo, const float* bo,
                           float* out)
{
  __shared__ float vec[512];
  __shared__ float a1[512];
  __shared__ float red[4];
  int b = blockIdx.x;
  int tid = threadIdx.x;   // 256
  for (int i = tid; i < 512; i += 256)
    vec[i] = fabsf(v[(size_t)b * 512 + i] - v[(size_t)(128 + b) * 512 + i]);
  __syncthreads();
  for (int j = tid; j < 512; j += 256) {
    float s = b1[j];
    const float* wr = W1 + (size_t)j * 512;
    for (int k = 0; k < 512; ++k) s += vec[k] * wr[k];
    a1[j] = fmaxf(s, 0.f);
  }
  __syncthreads();
  float s = b2[tid];
  {
    const float* wr = W2 + (size_t)tid * 512;
    for (int k = 0; k < 512; ++k) s += a1[k] * wr[k];
  }
  float p = fmaxf(s, 0.f) * Wo[tid];
  for (int off = 32; off > 0; off >>= 1) p += __shfl_down(p, off);
  if ((tid & 63) == 0) red[tid >> 6] = p;
  __syncthreads();
  if (tid == 0) {
    float logit = red[0] + red[1] + red[2] + red[3] + bo[0];
    out[b] = logit;
    out[128 + b] = 1.f / (1.f + __expf(-logit));
  }
}

extern "C" void kernel_launch(void* const* d_in, const int* in_sizes, int n_in,
                              void* d_out, int out_size, void* d_ws, size_t ws_size,
                              hipStream_t stream)
{
  const int*   x1    = (const int*)d_in[0];
  const int*   x2    = (const int*)d_in[1];
  const int*   len1  = (const int*)d_in[2];
  const int*   len2  = (const int*)d_in[3];
  const float* emb   = (const float*)d_in[4];
  const float* wih_f = (const float*)d_in[5];
  const float* whh_f = (const float*)d_in[6];
  const float* bih_f = (const float*)d_in[7];
  const float* bhh_f = (const float*)d_in[8];
  const float* wih_b = (const float*)d_in[9];
  const float* whh_b = (const float*)d_in[10];
  const float* bih_b = (const float*)d_in[11];
  const float* bhh_b = (const float*)d_in[12];
  const float* W1    = (const float*)d_in[13];
  const float* b1    = (const float*)d_in[14];
  const float* W2    = (const float*)d_in[15];
  const float* b2    = (const float*)d_in[16];
  const float* Wo    = (const float*)d_in[17];
  const float* bo    = (const float*)d_in[18];

  char* p = (char*)d_ws;
  u16*   wih_bf = (u16*)p;          p += SZ_WIH;
  char*  wpk    = (char*)p;         p += SZ_WPK;
  float* swp    = (float*)p;        p += SZ_SW;
  float* bias   = (float*)p;        p += SZ_BIAS;
  char*  hsave  = (char*)p;         p += SZ_HSV;
  float* cst    = (float*)p;        p += SZ_CST;
  float* vac    = (float*)p;        p += SZ_VAC;
  float* vout   = (float*)p;        p += SZ_VOUT;
  u16*   embbf  = (u16*)p;          p += SZ_EMB;

  int T = 256;
  while (T > 1 && FIXED_B + (size_t)T * PER_T > ws_size) T >>= 1;
  int logT = __builtin_ctz((unsigned)T);
  u16* ginc = (u16*)p;              // [(d*T+tl)*256 + R][1024 sigma-cols] u16 (+1 pad slab)

  {
    int total = 2 * 1024 * EPAD + 2 * 1024;
    prep_kernel<<<(total + 255) / 256, 256, 0, stream>>>(
        wih_f, bih_f, bhh_f, wih_b, bih_b, bhh_b, wih_bf, bias);
  }
  whhq_kernel<<<2048, 64, 0, stream>>>(whh_f, whh_b, wpk, swp);
  embconv_kernel<<<VOCAB, EPAD, 0, stream>>>(emb, embbf);

  int nch = 256 / T;
  for (int ch = 0; ch < nch; ++ch) {
    int tt0 = ch * T;
    gemm_chunk_kernel<<<dim3(4 * T), 256, 0, stream>>>(x1, x2, embbf, wih_bf, bias,
                                                       ginc, tt0, T, logT);
    lstm_chunk_kernel<<<256, 512, 0, stream>>>(ginc, (const i32x4*)wpk, swp, hsave,
                                               cst, vac, vout, len1, len2, tt0, T);
  }

  mlp_kernel<<<128, 256, 0, stream>>>(vout, W1, b1, W2, b2, Wo, bo, (float*)d_out);
}

// Round 15
// 480.551 us; speedup vs baseline: 1.5199x; 1.0416x over previous
//
#include <hip/hip_runtime.h>
#include <hip/hip_bf16.h>
#include <math.h>

typedef unsigned short u16;
typedef short s16x8 __attribute__((ext_vector_type(8)));
typedef float f32x4v __attribute__((ext_vector_type(4)));
typedef int i32x4 __attribute__((ext_vector_type(4)));
typedef unsigned short u16x4 __attribute__((ext_vector_type(4)));

#define EDIM 300
#define EPAD 320
#define VOCAB 50000

// ---- fixed workspace layout (bytes) ----
static constexpr size_t SZ_WIH  = (size_t)2 * 1024 * EPAD * 2;   // bf16 [2][1024 pack][320]
static constexpr size_t SZ_WPK  = (size_t)2 * 1024 * 256;        // i8 packed Whh frags
static constexpr size_t SZ_SW   = (size_t)2 * 1024 * 4;          // f32 per-row scale (pack order)
static constexpr size_t SZ_BIAS = (size_t)2 * 1024 * 4;          // f32 (pack order)
static constexpr size_t SZ_HSV  = (size_t)2 * 256 * 256;         // i8 h chunk-boundary save
static constexpr size_t SZ_CST  = (size_t)2 * 256 * 256 * 4;     // f32 c-state
static constexpr size_t SZ_VAC  = (size_t)2 * 256 * 256 * 4;     // f32 vacc-state
static constexpr size_t SZ_VOUT = (size_t)2 * 128 * 512 * 4;     // f32 [2][128][512]
static constexpr size_t SZ_EMB  = (size_t)VOCAB * EPAD * 2;      // bf16 emb table padded (32 MB)
static constexpr size_t SZ_PAD  = (size_t)512 * 1024;            // +1 slab: unclamped prefetch
static constexpr size_t FIXED_B = SZ_WIH + SZ_WPK + SZ_SW + SZ_BIAS + SZ_HSV + SZ_CST + SZ_VAC + SZ_VOUT + SZ_EMB + SZ_PAD;
static constexpr size_t PER_T   = (size_t)512 * 1024 * 2;        // ginc per step (1 MB, both dirs)

// pack permutation: pack p = w*128 + q*16 + ul  (w=wave 0..7, q=uh*4+gate, ul 0..15)
//   -> logical Whh/Wih row jlog = (q&3)*256 + w*32 + (q>>2)*16 + ul
// sigma (ginc column) s = w*128 + uh*64 + ul*4 + gate  (gates contiguous per cell)

__device__ __forceinline__ float bf2f(u16 u) {
  union { float f; unsigned int i; } v; v.i = ((unsigned int)u) << 16; return v.f;
}
__device__ __forceinline__ u16 f2bf(float f) {
  union { float f; unsigned int i; } v; v.f = f;
  unsigned int r = v.i + 0x7fffu + ((v.i >> 16) & 1u);   // RNE (finite inputs)
  return (u16)(r >> 16);
}
__device__ __forceinline__ void gload_lds16(const void* g, void* l) {
  __builtin_amdgcn_global_load_lds((const __attribute__((address_space(1))) void*)g,
                                   (__attribute__((address_space(3))) void*)l, 16, 0, 0);
}
// order LDS ops across waves WITHOUT draining vmcnt
__device__ __forceinline__ void lds_barrier() {
  asm volatile("s_waitcnt lgkmcnt(0)" ::: "memory");
  __builtin_amdgcn_s_barrier();
}
// intra-wave LDS exchange fence (R13 bug fix): pins write->read order vs compiler AA
__device__ __forceinline__ void wave_lds_fence() {
  asm volatile("s_waitcnt lgkmcnt(0)" ::: "memory");
  __builtin_amdgcn_sched_barrier(0);
}

// ---------------- prep: Wih->bf16 padded (pack-row order), bias sum (pack order) ----------------
__global__ void prep_kernel(const float* wih_f, const float* bih_f, const float* bhh_f,
                            const float* wih_b, const float* bih_b, const float* bhh_b,
                            u16* wih_bf, float* bias)
{
  int tid = blockIdx.x * blockDim.x + threadIdx.x;
  if (tid < 2 * 1024 * EPAD) {
    int d = tid / (1024 * EPAD); int rr = tid % (1024 * EPAD);
    int p = rr / EPAD; int k = rr % EPAD;
    int w = p >> 7, q = (p >> 4) & 7, ul = p & 15;
    int jlog = (q & 3) * 256 + w * 32 + (q >> 2) * 16 + ul;
    const float* wsrc = d ? wih_b : wih_f;
    wih_bf[tid] = (k < EDIM) ? f2bf(wsrc[(size_t)jlog * EDIM + k]) : (u16)0;
  }
  int t2 = tid - 2 * 1024 * EPAD;
  if (t2 >= 0 && t2 < 2 * 1024) {
    int d = t2 >> 10; int p = t2 & 1023;
    int w = p >> 7, q = (p >> 4) & 7, ul = p & 15;
    int jlog = (q & 3) * 256 + w * 32 + (q >> 2) * 16 + ul;
    bias[t2] = d ? (bih_b[jlog] + bhh_b[jlog]) : (bih_f[jlog] + bhh_f[jlog]);
  }
}

// ---------------- emb -> bf16, K padded 300->320 (one-time) ----------------
__global__ void embconv_kernel(const float* emb, u16* embbf)
{
  int r = blockIdx.x;
  int k = threadIdx.x;     // 320
  embbf[(size_t)r * EPAD + k] = (k < EDIM) ? f2bf(emb[(size_t)r * EDIM + k]) : (u16)0;
}

// ---------------- Whh -> i8 quant + MFMA-fragment pack (8-wave pack order) ----------------
__global__ void whhq_kernel(const float* whh_f, const float* whh_b, char* wpk, float* sw)
{
  int jp = blockIdx.x;             // 0..2047 = d*1024 + pack p
  int t = threadIdx.x;             // 64
  int d = jp >> 10, p = jp & 1023;
  int w = p >> 7, q = (p >> 4) & 7, ul = p & 15;
  int jlog = (q & 3) * 256 + w * 32 + (q >> 2) * 16 + ul;
  const float* src = (d ? whh_b : whh_f) + (size_t)jlog * 256;
  float v[4]; float m = 0.f;
  #pragma unroll
  for (int kk = 0; kk < 4; ++kk) { v[kk] = src[t * 4 + kk]; m = fmaxf(m, fabsf(v[kk])); }
  #pragma unroll
  for (int off = 32; off > 0; off >>= 1) m = fmaxf(m, __shfl_xor(m, off));
  float sunit = m / 127.f;
  if (sunit < 1e-30f) sunit = 1e-30f;
  unsigned int pk = 0;
  #pragma unroll
  for (int kk = 0; kk < 4; ++kk) {
    int qv = (int)rintf(v[kk] / sunit);
    qv = qv > 127 ? 127 : (qv < -127 ? -127 : qv);
    pk |= ((unsigned int)(qv & 255)) << (8 * kk);
  }
  // frag entry (d,w,q,kc,lane=kg*16+ul): bytes = Wq[jlog][kc*64+kg*16 .. +16)
  size_t base = ((((size_t)(d * 8 + w) * 8 + q) * 4 + (t >> 4)) * 64
                 + (((t >> 2) & 3) * 16 + ul)) * 16 + (t & 3) * 4;
  *(unsigned int*)&wpk[base] = pk;
  if (t == 0) sw[jp] = sunit / 127.f;
}

// ---------------- fused gather + input projection GEMM, full-N per block, 8 WAVES ----------------
// Block = 128 M-rows x full N=1024, 512 threads (2 waves/SIMD for latency hiding).
// A (token gather) staged ONCE full-K in 80KB LDS; B double-buffered 2x16KB from L2.
// Epilogue: direct sigma-permuted u16x4 stores.
__global__ void __launch_bounds__(512, 1)
gemm_chunk_kernel(const int* __restrict__ x1, const int* __restrict__ x2,
                  const u16* __restrict__ embbf, const u16* __restrict__ wih_bf,
                  const float* __restrict__ bias, u16* __restrict__ ginc,
                  int t0, int T, int logT)
{
  __shared__ __align__(16) u16 As[5 * 8192];    // 80KB: [kt][16 grp][1024B]
  __shared__ __align__(16) u16 Bs[2 * 8192];    // 32KB double buffer

  int m0 = blockIdx.x * 128;
  int d  = m0 >> (8 + logT);
  int tl = (m0 >> 8) & (T - 1);
  int R0 = m0 & 255;                 // 0 or 128
  int lane = threadIdx.x & 63;
  int w = threadIdx.x >> 6;          // 8 waves
  int wm = w >> 1, wn = w & 1;       // wave tile: 32 rows x 64 cols per nt-slice

  const int* x = (R0 >> 7) ? x2 : x1;
  int t = t0 + tl;
  int tpos = d ? (255 - t) : t;

  int ar  = lane >> 3;               // row within 8-row stripe
  int acb = (lane & 7) * 16;         // byte col (16B slot)
  int swz = ar << 4;

  // 2 staging rows per thread (8 waves x 8 ar x 2 = 128 rows)
  int toks[2];
  #pragma unroll
  for (int i = 0; i < 2; ++i) {
    int lrow = (i * 8 + w) * 8 + ar;
    toks[i] = x[((R0 + lrow) & 127) * 256 + tpos];
  }

  const char* Bbase = (const char*)(wih_bf + (size_t)d * 1024 * EPAD);
  const char* Ebase = (const char*)embbf;

  // stage full-K A (once) + B(nt=0, kt=0) into buf 0
  #pragma unroll
  for (int kt = 0; kt < 5; ++kt)
    #pragma unroll
    for (int i = 0; i < 2; ++i)
      gload_lds16(Ebase + (size_t)toks[i] * 640 + kt * 128 + (acb ^ swz),
                  (char*)As + kt * 16384 + (i * 8 + w) * 1024);
  #pragma unroll
  for (int i = 0; i < 2; ++i) {
    int lrow = (i * 8 + w) * 8 + ar;
    gload_lds16(Bbase + (size_t)lrow * 640 + (acb ^ swz),
                (char*)Bs + (i * 8 + w) * 1024);
  }
  __syncthreads();

  size_t rowbase = (size_t)(d * T + tl) * 256 + R0;
  int buf = 0;

  for (int nt = 0; nt < 8; ++nt) {
    f32x4v acc[2][4] = {};
    for (int kt = 0; kt < 5; ++kt) {
      // prefetch next B tile into buf^1
      int nkt = kt + 1, nnt = nt;
      if (nkt == 5) { nkt = 0; nnt = nt + 1; }
      if (nnt < 8) {
        #pragma unroll
        for (int i = 0; i < 2; ++i) {
          int lrow = nnt * 128 + (i * 8 + w) * 8 + ar;
          gload_lds16(Bbase + (size_t)lrow * 640 + nkt * 128 + (acb ^ swz),
                      (char*)Bs + (buf ^ 1) * 16384 + (i * 8 + w) * 1024);
        }
      }
      // compute As[kt] x Bs[buf]
      #pragma unroll
      for (int kc = 0; kc < 2; ++kc) {
        s16x8 a[2], b[4];
        int cb = kc * 64 + (lane >> 4) * 16;
        #pragma unroll
        for (int mf = 0; mf < 2; ++mf) {
          int rr = wm * 32 + mf * 16 + (lane & 15);
          a[mf] = *(const s16x8*)((const char*)As + kt * 16384 + rr * 128 + (cb ^ ((rr & 7) << 4)));
        }
        #pragma unroll
        for (int nf = 0; nf < 4; ++nf) {
          int rr = wn * 64 + nf * 16 + (lane & 15);
          b[nf] = *(const s16x8*)((const char*)Bs + buf * 16384 + rr * 128 + (cb ^ ((rr & 7) << 4)));
        }
        #pragma unroll
        for (int mf = 0; mf < 2; ++mf)
          #pragma unroll
          for (int nf = 0; nf < 4; ++nf)
            acc[mf][nf] = __builtin_amdgcn_mfma_f32_16x16x32_bf16(a[mf], b[nf], acc[mf][nf], 0, 0, 0);
      }
      __syncthreads();
      buf ^= 1;
    }

    // epilogue nt: bias, direct sigma store (u16x4 = 4 gates of one cell)
    float bv[4];
    #pragma unroll
    for (int nf = 0; nf < 4; ++nf)
      bv[nf] = bias[d * 1024 + nt * 128 + wn * 64 + nf * 16 + (lane & 15)];
    int scol = nt * 128 + wn * 64 + (lane & 15) * 4;
    #pragma unroll
    for (int mf = 0; mf < 2; ++mf)
      #pragma unroll
      for (int i = 0; i < 4; ++i) {
        int row = wm * 32 + mf * 16 + (lane >> 4) * 4 + i;
        u16x4 v;
        #pragma unroll
        for (int nf = 0; nf < 4; ++nf)
          v[nf] = f2bf(acc[mf][nf][i] + bv[nf]);
        *(u16x4*)(ginc + (rowbase + row) * 1024 + scol) = v;
      }
  }
}

// ---------------- recurrent bi-LSTM: R7 tiling + ALL-LANE gate math (fenced exchange) ----------------
// 256 blocks = 2 dir x 128 two-row tiles; 8 waves; wave w owns u in [w*32,(w+1)*32) x 4 gates.
// After MFMA, lanes<16 stage raw i32 preacts to a per-wave LDS slab [64 cells][4 gates];
// wave_lds_fence() pins write->read order; every lane reads ONE cell (cell idx == lane).
// ONE lgkm-only block barrier per step.
__global__ void __launch_bounds__(512)
lstm_chunk_kernel(const u16* __restrict__ ginc, const i32x4* __restrict__ wpk,
                  const float* __restrict__ sw, char* hsave,
                  float* cstate, float* vaccst, float* vout,
                  const int* len1, const int* len2, int t0, int T)
{
  __shared__ __align__(16) char h_lds[2][2][288];   // [parity][row][256 k +pad]
  __shared__ __align__(16) int gstage[8][64][4];    // [wave][cell][gate] raw i32 preacts

  const int bid = blockIdx.x;
  const int d = bid >> 7, bt = bid & 127;
  const int tid = threadIdx.x;
  const int lane = tid & 63, w = tid >> 6;          // 8 waves
  const int cl = lane & 15;

  // owned cell (all 64 lanes): lane = cr*32 + cuh*16 + cl
  const int cr  = lane >> 5;
  const int cuh = (lane >> 4) & 1;
  const int cu  = w * 32 + cuh * 16 + cl;           // u index of owned cell

  // Whh i8 fragments -> registers; per-owned-cell scales (pack order)
  i32x4 bfr[8][4];
  #pragma unroll
  for (int q = 0; q < 8; ++q)
    #pragma unroll
    for (int kc = 0; kc < 4; ++kc)
      bfr[q][kc] = wpk[(((size_t)(d * 8 + w) * 8 + q) * 4 + kc) * 64 + lane];
  float swl4[4];
  #pragma unroll
  for (int g = 0; g < 4; ++g)
    swl4[g] = sw[d * 1024 + w * 128 + (cuh * 4 + g) * 16 + cl];

  const int R0 = bt * 2;
  {
    int r = tid >> 8, u = tid & 255;
    h_lds[0][r][u] = (t0 > 0) ? hsave[((size_t)d * 256 + R0 + r) * 256 + u] : (char)0;
  }

  const int RR = R0 + cr;
  const int lm = ((RR >> 7) ? len2 : len1)[RR & 127] - 1;
  const size_t sidx = ((size_t)d * 256 + RR) * 256 + cu;
  float c = 0.f, va = 0.f;
  if (t0 > 0) { c = cstate[sidx]; va = vaccst[sidx]; }

  const size_t GSTEP = (size_t)256 * 1024;
  const u16* gcell = ginc + ((size_t)d * T * 256 + RR) * 1024 + w * 128 + cuh * 64 + cl * 4;
  u16x4 gv = *(const u16x4*)gcell;
  __syncthreads();

  const bool final_chunk = (t0 + T == 256);
  int par = 0;

  for (int tl = 0; tl < T; ++tl) {
    // prefetch next step's gates — unclamped (pad slab), flies across the barrier
    u16x4 gvn = *(const u16x4*)(gcell + GSTEP * (size_t)(tl + 1));

    // A-frags (rows 0,1 real; others zero) — mask is (cl<2) only:
    // rows live in lanes {0,1,16,17,32,33,48,49}; lane>>4 selects the k-segment.
    i32x4 a[4] = {{0,0,0,0},{0,0,0,0},{0,0,0,0},{0,0,0,0}};
    if (cl < 2) {
      #pragma unroll
      for (int kc = 0; kc < 4; ++kc)
        a[kc] = *(const i32x4*)&h_lds[par][cl][kc * 64 + (lane >> 4) * 16];
    }
    i32x4 acc[8];
    #pragma unroll
    for (int q = 0; q < 8; ++q) {
      i32x4 z = {0, 0, 0, 0};
      #pragma unroll
      for (int kc = 0; kc < 4; ++kc)
        z = __builtin_amdgcn_mfma_i32_16x16x64_i8(a[kc], bfr[q][kc], z, 0, 0, 0);
      acc[q] = z;
    }

    // stage raw preacts: lanes<16 hold cells (r2 = reg, uh2, ul=lane) of C/D rows 0,1
    if (lane < 16) {
      #pragma unroll
      for (int r2 = 0; r2 < 2; ++r2)
        #pragma unroll
        for (int uh2 = 0; uh2 < 2; ++uh2) {
          i32x4 v = { acc[uh2 * 4 + 0][r2], acc[uh2 * 4 + 1][r2],
                      acc[uh2 * 4 + 2][r2], acc[uh2 * 4 + 3][r2] };
          *(i32x4*)&gstage[w][r2 * 32 + uh2 * 16 + lane][0] = v;
        }
    }
    // FENCE: required — compiler may otherwise hoist the cross-lane read (R13 bug)
    wave_lds_fence();
    i32x4 g4 = *(const i32x4*)&gstage[w][lane][0];

    // gate math — ALL 64 lanes, 1 cell each
    {
      float s0 = (float)g4[0] * swl4[0] + bf2f(gv[0]);
      float s1 = (float)g4[1] * swl4[1] + bf2f(gv[1]);
      float s2 = (float)g4[2] * swl4[2] + bf2f(gv[2]);
      float s3 = (float)g4[3] * swl4[3] + bf2f(gv[3]);
      float I = __builtin_amdgcn_rcpf(1.f + __expf(-s0));
      float F = __builtin_amdgcn_rcpf(1.f + __expf(-s1));
      float G = 1.f - 2.f * __builtin_amdgcn_rcpf(__expf(2.f * s2) + 1.f);
      float O = __builtin_amdgcn_rcpf(1.f + __expf(-s3));
      float cn = F * c + I * G;
      c = cn;
      float hn = O * (1.f - 2.f * __builtin_amdgcn_rcpf(__expf(2.f * cn) + 1.f));
      int tmap = d ? (255 - (t0 + tl)) : (t0 + tl);
      if (tmap < lm) va += hn;
      h_lds[par ^ 1][cr][cu] = (char)(int)rintf(hn * 127.f);
    }
    lds_barrier();
    gv = gvn;
    par ^= 1;
  }

  cstate[sidx] = c;
  vaccst[sidx] = va;
  if (final_chunk) {
    vout[((size_t)(RR >> 7) * 128 + (RR & 127)) * 512 + d * 256 + cu] = va / (float)lm;
  } else {
    int r = tid >> 8, u = tid & 255;
    hsave[((size_t)d * 256 + R0 + r) * 256 + u] = h_lds[par][r][u];
  }
}

// ---------------- MLP head ----------------
__global__ void mlp_kernel(const float* v, const float* W1, const float* b1,
                           const float* W2, const float* b2, const float* Wo, const float* bo,
                           float* out)
{
  __shared__ float vec[512];
  __shared__ float a1[512];
  __shared__ float red[4];
  int b = blockIdx.x;
  int tid = threadIdx.x;   // 256
  for (int i = tid; i < 512; i += 256)
    vec[i] = fabsf(v[(size_t)b * 512 + i] - v[(size_t)(128 + b) * 512 + i]);
  __syncthreads();
  for (int j = tid; j < 512; j += 256) {
    float s = b1[j];
    const float* wr = W1 + (size_t)j * 512;
    for (int k = 0; k < 512; ++k) s += vec[k] * wr[k];
    a1[j] = fmaxf(s, 0.f);
  }
  __syncthreads();
  float s = b2[tid];
  {
    const float* wr = W2 + (size_t)tid * 512;
    for (int k = 0; k < 512; ++k) s += a1[k] * wr[k];
  }
  float p = fmaxf(s, 0.f) * Wo[tid];
  for (int off = 32; off > 0; off >>= 1) p += __shfl_down(p, off);
  if ((tid & 63) == 0) red[tid >> 6] = p;
  __syncthreads();
  if (tid == 0) {
    float logit = red[0] + red[1] + red[2] + red[3] + bo[0];
    out[b] = logit;
    out[128 + b] = 1.f / (1.f + __expf(-logit));
  }
}

extern "C" void kernel_launch(void* const* d_in, const int* in_sizes, int n_in,
                              void* d_out, int out_size, void* d_ws, size_t ws_size,
                              hipStream_t stream)
{
  const int*   x1    = (const int*)d_in[0];
  const int*   x2    = (const int*)d_in[1];
  const int*   len1  = (const int*)d_in[2];
  const int*   len2  = (const int*)d_in[3];
  const float* emb   = (const float*)d_in[4];
  const float* wih_f = (const float*)d_in[5];
  const float* whh_f = (const float*)d_in[6];
  const float* bih_f = (const float*)d_in[7];
  const float* bhh_f = (const float*)d_in[8];
  const float* wih_b = (const float*)d_in[9];
  const float* whh_b = (const float*)d_in[10];
  const float* bih_b = (const float*)d_in[11];
  const float* bhh_b = (const float*)d_in[12];
  const float* W1    = (const float*)d_in[13];
  const float* b1    = (const float*)d_in[14];
  const float* W2    = (const float*)d_in[15];
  const float* b2    = (const float*)d_in[16];
  const float* Wo    = (const float*)d_in[17];
  const float* bo    = (const float*)d_in[18];

  char* p = (char*)d_ws;
  u16*   wih_bf = (u16*)p;          p += SZ_WIH;
  char*  wpk    = (char*)p;         p += SZ_WPK;
  float* swp    = (float*)p;        p += SZ_SW;
  float* bias   = (float*)p;        p += SZ_BIAS;
  char*  hsave  = (char*)p;         p += SZ_HSV;
  float* cst    = (float*)p;        p += SZ_CST;
  float* vac    = (float*)p;        p += SZ_VAC;
  float* vout   = (float*)p;        p += SZ_VOUT;
  u16*   embbf  = (u16*)p;          p += SZ_EMB;

  int T = 256;
  while (T > 1 && FIXED_B + (size_t)T * PER_T > ws_size) T >>= 1;
  int logT = __builtin_ctz((unsigned)T);
  u16* ginc = (u16*)p;              // [(d*T+tl)*256 + R][1024 sigma-cols] u16 (+1 pad slab)

  {
    int total = 2 * 1024 * EPAD + 2 * 1024;
    prep_kernel<<<(total + 255) / 256, 256, 0, stream>>>(
        wih_f, bih_f, bhh_f, wih_b, bih_b, bhh_b, wih_bf, bias);
  }
  whhq_kernel<<<2048, 64, 0, stream>>>(whh_f, whh_b, wpk, swp);
  embconv_kernel<<<VOCAB, EPAD, 0, stream>>>(emb, embbf);

  int nch = 256 / T;
  for (int ch = 0; ch < nch; ++ch) {
    int tt0 = ch * T;
    gemm_chunk_kernel<<<dim3(4 * T), 512, 0, stream>>>(x1, x2, embbf, wih_bf, bias,
                                                       ginc, tt0, T, logT);
    lstm_chunk_kernel<<<256, 512, 0, stream>>>(ginc, (const i32x4*)wpk, swp, hsave,
                                               cst, vac, vout, len1, len2, tt0, T);
  }

  mlp_kernel<<<128, 256, 0, stream>>>(vout, W1, b1, W2, b2, Wo, bo, (float*)d_out);
}